// Round 5
// baseline (428.114 us; speedup 1.0000x reference)
//
#include <hip/hip_runtime.h>

#define N_NODES 32768
#define N_EDGES 524288

typedef __attribute__((ext_vector_type(8))) short short8;
typedef __attribute__((ext_vector_type(4))) float floatx4;

#define GLOBAL_AS __attribute__((address_space(1)))
#define LDS_AS __attribute__((address_space(3)))

__device__ __forceinline__ unsigned short f2bf(float x) {
    union { float f; unsigned u; } v; v.f = x;
    unsigned r = v.u + 0x7FFF + ((v.u >> 16) & 1);
    return (unsigned short)(r >> 16);
}
__device__ __forceinline__ float bf2f(unsigned short u) {
    union { unsigned u; float f; } v; v.u = ((unsigned)u) << 16;
    return v.f;
}

// ================================================================ graph preprocessing
// Atomic-free CSR build (round 7): LDS byte histograms -> dense -> prefix -> place.

__global__ __launch_bounds__(256) void k_hist(const int* __restrict__ src,
                                              const int* __restrict__ dst,
                                              unsigned int* __restrict__ histOut32,
                                              unsigned int* __restrict__ histIn32) {
    __shared__ unsigned int hOut[8192];
    __shared__ unsigned int hIn[8192];
    int t = threadIdx.x, b = blockIdx.x;
    for (int i = t; i < 8192; i += 256) { hOut[i] = 0; hIn[i] = 0; }
    __syncthreads();
    int base = b * 4096;
    for (int i = t; i < 4096; i += 256) {
        int s = src[base + i], d = dst[base + i];
        atomicAdd(&hOut[s >> 2], 1u << ((s & 3) * 8));
        atomicAdd(&hIn[d >> 2], 1u << ((d & 3) * 8));
    }
    __syncthreads();
    for (int i = t; i < 8192; i += 256) {
        histOut32[b * 8192 + i] = hOut[i];
        histIn32[b * 8192 + i] = hIn[i];
    }
}

__global__ __launch_bounds__(256) void k_merge(const unsigned int* __restrict__ histOut32,
                                               const unsigned int* __restrict__ histIn32,
                                               unsigned int* __restrict__ pre32,
                                               int* __restrict__ in_deg,
                                               float* __restrict__ ns,
                                               float* __restrict__ nd) {
    int g = blockIdx.x * 256 + threadIdx.x;
    int ri0 = 0, ri1 = 0, ri2 = 0, ri3 = 0;
    for (int b = 0; b < 128; b++) {
        pre32[b * 8192 + g] = (unsigned)ri0 | ((unsigned)ri1 << 8) |
                              ((unsigned)ri2 << 16) | ((unsigned)ri3 << 24);
        unsigned int v = histIn32[b * 8192 + g];
        ri0 += v & 255; ri1 += (v >> 8) & 255; ri2 += (v >> 16) & 255; ri3 += (v >> 24) & 255;
    }
    in_deg[g * 4 + 0] = ri0; in_deg[g * 4 + 1] = ri1;
    in_deg[g * 4 + 2] = ri2; in_deg[g * 4 + 3] = ri3;
    nd[g * 4 + 0] = ri0 > 0 ? rsqrtf((float)ri0) : 1.0f;
    nd[g * 4 + 1] = ri1 > 0 ? rsqrtf((float)ri1) : 1.0f;
    nd[g * 4 + 2] = ri2 > 0 ? rsqrtf((float)ri2) : 1.0f;
    nd[g * 4 + 3] = ri3 > 0 ? rsqrtf((float)ri3) : 1.0f;
    int ro0 = 0, ro1 = 0, ro2 = 0, ro3 = 0;
    for (int b = 0; b < 128; b++) {
        unsigned int v = histOut32[b * 8192 + g];
        ro0 += v & 255; ro1 += (v >> 8) & 255; ro2 += (v >> 16) & 255; ro3 += (v >> 24) & 255;
    }
    ns[g * 4 + 0] = ro0 > 0 ? rsqrtf((float)ro0) : 1.0f;
    ns[g * 4 + 1] = ro1 > 0 ? rsqrtf((float)ro1) : 1.0f;
    ns[g * 4 + 2] = ro2 > 0 ? rsqrtf((float)ro2) : 1.0f;
    ns[g * 4 + 3] = ro3 > 0 ? rsqrtf((float)ro3) : 1.0f;
}

__global__ void k_scan(const int* __restrict__ in_deg, int* __restrict__ row_ptr) {
    __shared__ int part[1024];
    int t = threadIdx.x;
    int base = t * 32;
    int local[32];
    int s = 0;
    for (int i = 0; i < 32; i++) { local[i] = s; s += in_deg[base + i]; }
    part[t] = s;
    __syncthreads();
    for (int off = 1; off < 1024; off <<= 1) {
        int v = (t >= off) ? part[t - off] : 0;
        __syncthreads();
        part[t] += v;
        __syncthreads();
    }
    int prev = (t == 0) ? 0 : part[t - 1];
    for (int i = 0; i < 32; i++) row_ptr[base + i] = prev + local[i];
    if (t == 1023) row_ptr[N_NODES] = part[1023];
}

__global__ __launch_bounds__(256) void k_place(const int* __restrict__ src,
                                               const int* __restrict__ dst,
                                               const unsigned int* __restrict__ pre32,
                                               const int* __restrict__ row_ptr,
                                               int* __restrict__ csr_src) {
    __shared__ unsigned int cur[8192];
    int t = threadIdx.x, b = blockIdx.x;
    for (int i = t; i < 8192; i += 256) cur[i] = 0;
    __syncthreads();
    int base = b * 4096;
    const unsigned int* preb = pre32 + b * 8192;
    for (int i = t; i < 4096; i += 256) {
        int s = src[base + i], d = dst[base + i];
        int sh = (d & 3) * 8;
        unsigned int old = atomicAdd(&cur[d >> 2], 1u << sh);
        int rank = (old >> sh) & 255;
        int pb = (preb[d >> 2] >> sh) & 255;
        csr_src[row_ptr[d] + pb + rank] = s;
    }
}

// ---------------------------------------------- all 6 weight transposes in ONE kernel
struct TransDescs {
    const float* W[6];
    unsigned short* Wt[6];
    int K[6], N[6];
    int end[6];
};

__global__ __launch_bounds__(256) void k_transpose_all(TransDescs d) {
    int id = blockIdx.x, s = 0;
#pragma unroll
    for (int i = 0; i < 6; i++) if (id >= d.end[i]) s = i + 1;
    int base = (s == 0) ? 0 : d.end[s - 1];
    int t = id - base;
    int K = d.K[s], N = d.N[s];
    int ncols = N >> 5;
    int n0 = (t % ncols) * 32, k0 = (t / ncols) * 32;
    const float* W = d.W[s];
    unsigned short* Wt = d.Wt[s];
    __shared__ float tile[32][33];
    int tx = threadIdx.x & 31, ty = threadIdx.x >> 5;
    for (int r = 0; r < 32; r += 8)
        tile[ty + r][tx] = W[(size_t)(k0 + ty + r) * N + n0 + tx];
    __syncthreads();
    for (int r = 0; r < 32; r += 8)
        Wt[(size_t)(n0 + ty + r) * K + k0 + tx] = f2bf(tile[tx][ty + r]);
}

// ---------------------------------------------- x * ns[node] -> CHUNK-MAJOR bf16 table
// Gather table layout: 4 slabs of [N_NODES][64 feats] (4 MiB each == one XCD L2).
// Address of (node n, feat f) in shorts: (f>>6)*(N_NODES*64) + n*64 + (f&63).
__global__ __launch_bounds__(256) void k_scale_x(const float* __restrict__ x,
                                                 const float* __restrict__ ns,
                                                 unsigned short* __restrict__ xsb) {
    int i = blockIdx.x * 256 + threadIdx.x;  // float4 index
    float4 v = ((const float4*)x)[i];
    int n = i >> 6;           // 64 float4 per node
    int f = (i & 63) * 4;     // feature offset (multiple of 4)
    float sc = ns[n];
    ushort4 o;
    o.x = f2bf(v.x * sc); o.y = f2bf(v.y * sc);
    o.z = f2bf(v.z * sc); o.w = f2bf(v.w * sc);
    size_t off = (size_t)(f >> 6) * (N_NODES * 64) + (size_t)n * 64 + (f & 63);
    *(ushort4*)(xsb + off) = o;
}

// ------------------------------------------------ aggregation (gather, CSR by dst)
// Round 10 structure (proven ~24us): thread = (node, 16B window), full edge list,
// 8-edge unroll, blocks of 128 threads / 16 nodes, 16 blocks/CU = 32 waves/CU.
// Round 11: aggb store back to NONTEMPORAL (r2->r3 regression variable): aggb's
// consumer is 7/8 on a remote XCD, so dirty-L2 residency is useless; stream to L3.
__global__ __launch_bounds__(128, 8) void k_aggregate(
        const unsigned short* __restrict__ hs,   // chunk-major [4][N_NODES][64]
        const int* __restrict__ row_ptr,
        const int* __restrict__ csr_src,
        const float* __restrict__ nd,
        unsigned short* __restrict__ aggb) {     // row-major [N_NODES][256]
    __shared__ int eIdx[512];
    __shared__ int rp[17];
    const int tid = threadIdx.x;
    const int n0 = blockIdx.x * 16;
    if (tid <= 16) rp[tid] = row_ptr[n0 + tid];
    __syncthreads();
    const int ebeg = rp[0];
    const int ecount = rp[16] - ebeg;
    const int ecached = ecount < 512 ? ecount : 512;
    for (int i = tid; i < ecached; i += 128) eIdx[i] = csr_src[ebeg + i];
    __syncthreads();

    const int nl = tid >> 3;     // node local 0..15
    const int fs = tid & 7;      // 16B window within 64-feat chunk
    const int n = n0 + nl;
    const int beg = rp[nl] - ebeg, end = rp[nl + 1] - ebeg;
    const float sc = nd[n];

    auto sweep = [&](auto fetch) {
        for (int c = 0; c < 4; c++) {
            const unsigned short* hp = hs + (size_t)c * (N_NODES * 64) + fs * 8;
            float acc[8];
#pragma unroll
            for (int k = 0; k < 8; k++) acc[k] = 0.f;
            int e = beg;
            for (; e + 8 <= end; e += 8) {
                int s0 = fetch(e),     s1 = fetch(e + 1), s2 = fetch(e + 2), s3 = fetch(e + 3);
                int s4 = fetch(e + 4), s5 = fetch(e + 5), s6 = fetch(e + 6), s7 = fetch(e + 7);
                short8 v0 = *(const short8*)(hp + (size_t)s0 * 64);
                short8 v1 = *(const short8*)(hp + (size_t)s1 * 64);
                short8 v2 = *(const short8*)(hp + (size_t)s2 * 64);
                short8 v3 = *(const short8*)(hp + (size_t)s3 * 64);
                short8 v4 = *(const short8*)(hp + (size_t)s4 * 64);
                short8 v5 = *(const short8*)(hp + (size_t)s5 * 64);
                short8 v6 = *(const short8*)(hp + (size_t)s6 * 64);
                short8 v7 = *(const short8*)(hp + (size_t)s7 * 64);
#pragma unroll
                for (int k = 0; k < 8; k++)
                    acc[k] += ((bf2f((unsigned short)v0[k]) + bf2f((unsigned short)v1[k])) +
                               (bf2f((unsigned short)v2[k]) + bf2f((unsigned short)v3[k]))) +
                              ((bf2f((unsigned short)v4[k]) + bf2f((unsigned short)v5[k])) +
                               (bf2f((unsigned short)v6[k]) + bf2f((unsigned short)v7[k])));
            }
            for (; e + 2 <= end; e += 2) {
                int s0 = fetch(e), s1 = fetch(e + 1);
                short8 v0 = *(const short8*)(hp + (size_t)s0 * 64);
                short8 v1 = *(const short8*)(hp + (size_t)s1 * 64);
#pragma unroll
                for (int k = 0; k < 8; k++)
                    acc[k] += bf2f((unsigned short)v0[k]) + bf2f((unsigned short)v1[k]);
            }
            if (e < end) {
                int s = fetch(e);
                short8 v = *(const short8*)(hp + (size_t)s * 64);
#pragma unroll
                for (int k = 0; k < 8; k++) acc[k] += bf2f((unsigned short)v[k]);
            }
            short8 o;
#pragma unroll
            for (int k = 0; k < 8; k++) o[k] = (short)f2bf(acc[k] * sc);
            __builtin_nontemporal_store(o, (short8*)(aggb + (size_t)n * 256 + c * 64 + fs * 8));
        }
    };
    if (ecount <= 512)
        sweep([&](int e) { return eIdx[e]; });           // hot path: LDS-only indices
    else
        sweep([&](int e) { return csr_src[ebeg + e]; }); // ~never: correctness fallback
}

// ------------------------------------------------ fused 256-wide GEMM + leaky + LN + *ns
// Round 11: 64-row tiles (grid 512 = 2 blocks/CU, was 1), LDS 52->42.5 KB.
// Waves: 2 (row) x 2 (col); per wave acc[2][8] = 32 rows x 128 cols.
// Epilogue stores nontemporal (consumer is cross-XCD next-layer gather).
__global__ __launch_bounds__(256, 2) void gemm_ln(
        const unsigned short* __restrict__ A, const unsigned short* __restrict__ Bt,
        const float* __restrict__ bias, const float* __restrict__ ns,
        unsigned short* __restrict__ hsb) {
    __shared__ __align__(16) unsigned short As[2][64 * 32];
    __shared__ __align__(16) unsigned short Bs[2][256 * 32];
    __shared__ float sSum[2][64], sSum2[2][64], sMa[64], sMb[64];
    const int tid = threadIdx.x;
    const int lane = tid & 63;
    const int w = tid >> 6;
    const int wr = (w >> 1) * 32;
    const int wc = (w & 1) * 128;
    const int rowBase = blockIdx.x * 64;
    const int K = 256;

    floatx4 acc[2][8];
#pragma unroll
    for (int i = 0; i < 2; i++)
#pragma unroll
        for (int j = 0; j < 8; j++) acc[i][j] = (floatx4){0.f, 0.f, 0.f, 0.f};

    const int pr = lane >> 3;
    const int uu = (lane & 7) ^ pr;
    const int rowInGrp = pr * 2 + (uu >> 2);
    const int kc = (uu & 3) * 8;
    const unsigned short* gA = A + (size_t)(rowBase + w * 16 + rowInGrp) * K + kc;
    const unsigned short* gB = Bt + (size_t)(w * 64 + rowInGrp) * K + kc;
    const int aBase = (w * 16) * 32;
    const int bBase = (w * 64) * 32;

    const int q = lane >> 4;
    const int ln = lane & 15;
    const int uf = (((ln & 1) << 2) | q) ^ ((ln >> 1) & 7);

#define STAGE(buf_, koff_)                                                               \
    {                                                                                    \
        unsigned short* lA = As[buf_] + aBase;                                           \
        unsigned short* lB = Bs[buf_] + bBase;                                           \
        __builtin_amdgcn_global_load_lds((const GLOBAL_AS short*)(gA + (koff_)),         \
                                         (LDS_AS short*)lA, 16, 0, 0);                   \
        __builtin_amdgcn_global_load_lds((const GLOBAL_AS short*)(gB + (koff_)),         \
                                         (LDS_AS short*)lB, 16, 0, 0);                   \
        __builtin_amdgcn_global_load_lds((const GLOBAL_AS short*)(gB + (koff_) + (size_t)16 * K), \
                                         (LDS_AS short*)(lB + 16 * 32), 16, 0, 0);       \
        __builtin_amdgcn_global_load_lds((const GLOBAL_AS short*)(gB + (koff_) + (size_t)32 * K), \
                                         (LDS_AS short*)(lB + 32 * 32), 16, 0, 0);       \
        __builtin_amdgcn_global_load_lds((const GLOBAL_AS short*)(gB + (koff_) + (size_t)48 * K), \
                                         (LDS_AS short*)(lB + 48 * 32), 16, 0, 0);       \
    }

    STAGE(0, 0)
    int buf = 0;
    for (int k0 = 0; k0 < K; k0 += 32) {
        __syncthreads();
        if (k0 + 32 < K) STAGE(buf ^ 1, k0 + 32)
        const unsigned short* rA = As[buf];
        const unsigned short* rB = Bs[buf];
        short8 af[2], bfr[8];
#pragma unroll
        for (int i = 0; i < 2; i++)
            af[i] = *(const short8*)(rA + (((wr + i * 16 + ln) >> 1) << 6) + uf * 8);
#pragma unroll
        for (int j = 0; j < 8; j++)
            bfr[j] = *(const short8*)(rB + (((wc + j * 16 + ln) >> 1) << 6) + uf * 8);
#pragma unroll
        for (int i = 0; i < 2; i++)
#pragma unroll
            for (int j = 0; j < 8; j++)
                acc[i][j] = __builtin_amdgcn_mfma_f32_16x16x32_bf16(af[i], bfr[j], acc[i][j], 0, 0, 0);
        buf ^= 1;
    }
#undef STAGE

    float bcol[8];
#pragma unroll
    for (int j = 0; j < 8; j++) bcol[j] = bias[wc + j * 16 + ln];
    const int wcIdx = w & 1;
#pragma unroll
    for (int i = 0; i < 2; i++) {
#pragma unroll
        for (int r = 0; r < 4; r++) {
            float s = 0.f, s2 = 0.f;
#pragma unroll
            for (int j = 0; j < 8; j++) {
                float v = acc[i][j][r] + bcol[j];
                v = v >= 0.f ? v : 0.01f * v;
                s += v; s2 += v * v;
            }
#pragma unroll
            for (int off = 8; off > 0; off >>= 1) {
                s += __shfl_down(s, off, 16);
                s2 += __shfl_down(s2, off, 16);
            }
            if (ln == 0) {
                int row = wr + i * 16 + q * 4 + r;
                sSum[wcIdx][row] = s;
                sSum2[wcIdx][row] = s2;
            }
        }
    }
    __syncthreads();
    if (tid < 64) {
        float mu = (sSum[0][tid] + sSum[1][tid]) * (1.0f / 256.0f);
        float var = (sSum2[0][tid] + sSum2[1][tid]) * (1.0f / 256.0f) - mu * mu;
        float rs = rsqrtf(var + 1e-5f);
        float nsv = ns[rowBase + tid];
        sMa[tid] = rs * nsv;
        sMb[tid] = -mu * rs * nsv;
    }
    __syncthreads();
#pragma unroll
    for (int i = 0; i < 2; i++) {
#pragma unroll
        for (int r = 0; r < 4; r++) {
            int row = wr + i * 16 + q * 4 + r;
            float a = sMa[row], bb = sMb[row];
#pragma unroll
            for (int j = 0; j < 8; j++) {
                float v = acc[i][j][r] + bcol[j];
                v = v >= 0.f ? v : 0.01f * v;
                int col = wc + j * 16 + ln;
                size_t off = (size_t)(col >> 6) * (N_NODES * 64) +
                             (size_t)(rowBase + row) * 64 + (col & 63);
                __builtin_nontemporal_store(f2bf(v * a + bb), hsb + off);
            }
        }
    }
}

// ------------------------------------------------ bf16 MFMA GEMM (layer 4 + heads)
template <bool LEAKY, bool OUT_BF16, bool SPLIT>
__global__ __launch_bounds__(256) void gemm_mfma(
        const unsigned short* __restrict__ A, const unsigned short* __restrict__ Bt,
        const float* __restrict__ bias, const float* __restrict__ bias2,
        void* __restrict__ Cv, void* __restrict__ C2v,
        int M, int N, int K) {
    __shared__ __align__(16) unsigned short As[2][128 * 32];
    __shared__ __align__(16) unsigned short Bs[2][128 * 32];
    const int tid = threadIdx.x;
    const int lane = tid & 63;
    const int w = tid >> 6;
    const int wr = (w >> 1) * 64;
    const int wc = (w & 1) * 64;
    const int rowBase = blockIdx.x * 128;
    const int colBase = blockIdx.y * 128;

    floatx4 acc[4][4];
#pragma unroll
    for (int i = 0; i < 4; i++)
#pragma unroll
        for (int j = 0; j < 4; j++) acc[i][j] = (floatx4){0.f, 0.f, 0.f, 0.f};

    const int pr = lane >> 3;
    const int uu = (lane & 7) ^ pr;
    const int srow = w * 32 + pr * 2 + (uu >> 2);
    const int kc = (uu & 3) * 8;
    const unsigned short* gA = A + (size_t)(rowBase + srow) * K + kc;
    const unsigned short* gB = Bt + (size_t)(colBase + srow) * K + kc;
    const int wbase = (w * 32) * 32;

    const int q = lane >> 4;
    const int ln = lane & 15;
    const int uf = (((ln & 1) << 2) | q) ^ ((ln >> 1) & 7);

    {
        unsigned short* lA = As[0] + wbase;
        unsigned short* lB = Bs[0] + wbase;
        __builtin_amdgcn_global_load_lds((const GLOBAL_AS short*)(gA),
                                         (LDS_AS short*)lA, 16, 0, 0);
        __builtin_amdgcn_global_load_lds((const GLOBAL_AS short*)(gA + (size_t)16 * K),
                                         (LDS_AS short*)(lA + 16 * 32), 16, 0, 0);
        __builtin_amdgcn_global_load_lds((const GLOBAL_AS short*)(gB),
                                         (LDS_AS short*)lB, 16, 0, 0);
        __builtin_amdgcn_global_load_lds((const GLOBAL_AS short*)(gB + (size_t)16 * K),
                                         (LDS_AS short*)(lB + 16 * 32), 16, 0, 0);
    }

    int buf = 0;
    for (int k0 = 0; k0 < K; k0 += 32) {
        __syncthreads();
        if (k0 + 32 < K) {
            unsigned short* lA = As[buf ^ 1] + wbase;
            unsigned short* lB = Bs[buf ^ 1] + wbase;
            __builtin_amdgcn_global_load_lds((const GLOBAL_AS short*)(gA + k0 + 32),
                                             (LDS_AS short*)lA, 16, 0, 0);
            __builtin_amdgcn_global_load_lds((const GLOBAL_AS short*)(gA + k0 + 32 + (size_t)16 * K),
                                             (LDS_AS short*)(lA + 16 * 32), 16, 0, 0);
            __builtin_amdgcn_global_load_lds((const GLOBAL_AS short*)(gB + k0 + 32),
                                             (LDS_AS short*)lB, 16, 0, 0);
            __builtin_amdgcn_global_load_lds((const GLOBAL_AS short*)(gB + k0 + 32 + (size_t)16 * K),
                                             (LDS_AS short*)(lB + 16 * 32), 16, 0, 0);
        }
        const unsigned short* rA = As[buf];
        const unsigned short* rB = Bs[buf];
        short8 af[4], bfr[4];
#pragma unroll
        for (int i = 0; i < 4; i++)
            af[i] = *(const short8*)(rA + (((wr + i * 16 + ln) >> 1) << 6) + uf * 8);
#pragma unroll
        for (int j = 0; j < 4; j++)
            bfr[j] = *(const short8*)(rB + (((wc + j * 16 + ln) >> 1) << 6) + uf * 8);
#pragma unroll
        for (int i = 0; i < 4; i++)
#pragma unroll
            for (int j = 0; j < 4; j++)
                acc[i][j] = __builtin_amdgcn_mfma_f32_16x16x32_bf16(af[i], bfr[j], acc[i][j], 0, 0, 0);
        buf ^= 1;
    }
    const int NH = N >> 1;
#pragma unroll
    for (int i = 0; i < 4; i++) {
#pragma unroll
        for (int j = 0; j < 4; j++) {
#pragma unroll
            for (int r = 0; r < 4; r++) {
                int row = rowBase + wr + i * 16 + q * 4 + r;
                int col = colBase + wc + j * 16 + ln;
                float b, *Cf; int cw, ccol;
                if (SPLIT) {
                    bool hi = col >= NH;
                    b = hi ? bias2[col - NH] : bias[col];
                    Cf = (float*)(hi ? C2v : Cv);
                    cw = NH; ccol = hi ? col - NH : col;
                } else {
                    b = bias[col];
                    Cf = (float*)Cv;
                    cw = N; ccol = col;
                }
                float v = acc[i][j][r] + b;
                if (LEAKY) v = v >= 0.f ? v : 0.01f * v;
                if (OUT_BF16)
                    __builtin_nontemporal_store(f2bf(v),
                        (unsigned short*)Cv + (size_t)row * cw + ccol);
                else
                    Cf[(size_t)row * cw + ccol] = v;
            }
        }
    }
}

// ------------------------------------------------ fused per-node LN(1024) + partial mean-pool
__global__ __launch_bounds__(256) void k_lnpool(const unsigned short* __restrict__ h4,
                                                float* __restrict__ partial) {
    const int g = blockIdx.y, p = blockIdx.x;
    const int w = threadIdx.x >> 6, lane = threadIdx.x & 63;
    float acc[16];
#pragma unroll
    for (int k = 0; k < 16; k++) acc[k] = 0.f;
    for (int i = 0; i < 8; i++) {
        int node = (g * 8 + p) * 32 + w * 8 + i;
        const unsigned short* row = h4 + (size_t)node * 1024 + lane * 16;
        short8 a = *(const short8*)row;
        short8 b = *(const short8*)(row + 8);
        float v[16];
#pragma unroll
        for (int k = 0; k < 8; k++) v[k] = bf2f((unsigned short)a[k]);
#pragma unroll
        for (int k = 0; k < 8; k++) v[8 + k] = bf2f((unsigned short)b[k]);
        float s = 0.f, s2 = 0.f;
#pragma unroll
        for (int k = 0; k < 16; k++) { s += v[k]; s2 += v[k] * v[k]; }
#pragma unroll
        for (int off = 32; off > 0; off >>= 1) {
            s += __shfl_down(s, off);
            s2 += __shfl_down(s2, off);
        }
        s = __shfl(s, 0);
        s2 = __shfl(s2, 0);
        float mu = s * (1.0f / 1024.0f);
        float var = s2 * (1.0f / 1024.0f) - mu * mu;
        float rs = rsqrtf(var + 1e-5f);
#pragma unroll
        for (int k = 0; k < 16; k++) acc[k] += (v[k] - mu) * rs;
    }
    __shared__ float red[4][1024];
    float* my = red[w] + lane * 16;
#pragma unroll
    for (int k = 0; k < 16; k++) my[k] = acc[k];
    __syncthreads();
    int t = threadIdx.x;
    floatx4 o = (floatx4){0.f, 0.f, 0.f, 0.f};
#pragma unroll
    for (int w2 = 0; w2 < 4; w2++) {
        const floatx4 v = *(const floatx4*)(red[w2] + t * 4);
        o += v;
    }
    __builtin_nontemporal_store(o, (floatx4*)(partial + (size_t)(g * 8 + p) * 1024 + t * 4));
}

__global__ __launch_bounds__(256) void k_pool_final(const float* __restrict__ partial,
                                                    unsigned short* __restrict__ pooledb) {
    int g = blockIdx.x, t = threadIdx.x;
    int wave = t >> 6;
    float4 a = make_float4(0.f, 0.f, 0.f, 0.f);
    for (int p = 0; p < 8; p++) {
        float4 v = *(const float4*)(partial + (size_t)(g * 8 + p) * 1024 + t * 4);
        a.x += v.x; a.y += v.y; a.z += v.z; a.w += v.w;
    }
    const float invn = 1.0f / 256.0f;
    a.x *= invn; a.y *= invn; a.z *= invn; a.w *= invn;
    float s = a.x + a.y + a.z + a.w;
    float s2 = a.x * a.x + a.y * a.y + a.z * a.z + a.w * a.w;
#pragma unroll
    for (int off = 32; off > 0; off >>= 1) {
        s += __shfl_down(s, off);
        s2 += __shfl_down(s2, off);
    }
    __shared__ float ss[4], ss2[4];
    if ((t & 63) == 0) { ss[wave] = s; ss2[wave] = s2; }
    __syncthreads();
    if (t == 0) {
        float tt = 0.f, tt2 = 0.f;
        for (int w = 0; w < 4; w++) { tt += ss[w]; tt2 += ss2[w]; }
        float mu = tt / 1024.f;
        float var = tt2 / 1024.f - mu * mu;
        ss[0] = mu;
        ss2[0] = rsqrtf(var + 1e-5f);
    }
    __syncthreads();
    float mu = ss[0], inv = ss2[0];
    ushort4 o;
    o.x = f2bf((a.x - mu) * inv); o.y = f2bf((a.y - mu) * inv);
    o.z = f2bf((a.z - mu) * inv); o.w = f2bf((a.w - mu) * inv);
    *(ushort4*)(pooledb + (size_t)g * 1024 + t * 4) = o;
}

// ---------------------------------------------------------------- launch
extern "C" void kernel_launch(void* const* d_in, const int* in_sizes, int n_in,
                              void* d_out, int out_size, void* d_ws, size_t ws_size,
                              hipStream_t stream) {
    const float* x  = (const float*)d_in[0];
    const int*   src = (const int*)d_in[1];
    const int*   dst = (const int*)d_in[2];
    const float* W1 = (const float*)d_in[3];  const float* b1 = (const float*)d_in[4];
    const float* W2 = (const float*)d_in[5];  const float* b2 = (const float*)d_in[6];
    const float* W3 = (const float*)d_in[7];  const float* b3 = (const float*)d_in[8];
    const float* W4 = (const float*)d_in[9];  const float* b4 = (const float*)d_in[10];
    const float* Wm = (const float*)d_in[11]; const float* bm = (const float*)d_in[12];
    const float* Wsd = (const float*)d_in[13]; const float* bsd = (const float*)d_in[14];
    float* out = (float*)d_out;

    char* w = (char*)d_ws;
    unsigned short* aggb = (unsigned short*)w; w += (size_t)N_NODES * 256 * 2;
    unsigned short* hsb  = (unsigned short*)w; w += (size_t)N_NODES * 256 * 2;
    unsigned short* h4b  = (unsigned short*)w; w += (size_t)N_NODES * 1024 * 2;
    float* partial = (float*)w; w += (size_t)128 * 8 * 1024 * 4;
    unsigned short* pooledb = (unsigned short*)w; w += (size_t)128 * 1024 * 2;
    unsigned short* W1t = (unsigned short*)w; w += (size_t)256 * 256 * 2;
    unsigned short* W2t = (unsigned short*)w; w += (size_t)256 * 256 * 2;
    unsigned short* W3t = (unsigned short*)w; w += (size_t)256 * 256 * 2;
    unsigned short* W4t = (unsigned short*)w; w += (size_t)256 * 1024 * 2;
    unsigned short* Wmt = (unsigned short*)w; w += (size_t)1024 * 1024 * 2;  // Wst must follow
    unsigned short* Wst = (unsigned short*)w; w += (size_t)1024 * 1024 * 2;  // contiguous: cat
    float* ns     = (float*)w; w += (size_t)N_NODES * 4;
    float* nd     = (float*)w; w += (size_t)N_NODES * 4;
    unsigned int* histOut32 = (unsigned int*)w; w += (size_t)128 * 8192 * 4;
    unsigned int* histIn32  = (unsigned int*)w; w += (size_t)128 * 8192 * 4;
    unsigned int* pre32     = (unsigned int*)w; w += (size_t)128 * 8192 * 4;
    int* in_deg   = (int*)w;   w += (size_t)N_NODES * 4;
    int* row_ptr  = (int*)w;   w += (size_t)(N_NODES + 1) * 4;
    int* csr_src  = (int*)w;   w += (size_t)N_EDGES * 4;

    // weights (independent of graph work)
    TransDescs td;
    td.W[0] = W1; td.W[1] = W2; td.W[2] = W3; td.W[3] = W4; td.W[4] = Wm; td.W[5] = Wsd;
    td.Wt[0] = W1t; td.Wt[1] = W2t; td.Wt[2] = W3t; td.Wt[3] = W4t; td.Wt[4] = Wmt; td.Wt[5] = Wst;
    td.K[0] = 256; td.K[1] = 256; td.K[2] = 256; td.K[3] = 256; td.K[4] = 1024; td.K[5] = 1024;
    td.N[0] = 256; td.N[1] = 256; td.N[2] = 256; td.N[3] = 1024; td.N[4] = 1024; td.N[5] = 1024;
    td.end[0] = 64; td.end[1] = 128; td.end[2] = 192; td.end[3] = 448; td.end[4] = 1472; td.end[5] = 2496;
    k_transpose_all<<<2496, 256, 0, stream>>>(td);

    // atomic-free graph preprocessing
    k_hist<<<128, 256, 0, stream>>>(src, dst, histOut32, histIn32);
    k_merge<<<32, 256, 0, stream>>>(histOut32, histIn32, pre32, in_deg, ns, nd);
    k_scan<<<1, 1024, 0, stream>>>(in_deg, row_ptr);
    k_place<<<128, 256, 0, stream>>>(src, dst, pre32, row_ptr, csr_src);

    // layer-1 gather table: x * ns -> bf16 (chunk-major slabs)
    k_scale_x<<<N_NODES * 256 / 1024, 256, 0, stream>>>(x, ns, hsb);

    // layers 1-3: high-occupancy aggregate -> fused GEMM+leaky+LN+*ns -> chunk-major table
    const unsigned short* Wts[3] = {W1t, W2t, W3t};
    const float* bs3[3] = {b1, b2, b3};
    for (int l = 0; l < 3; l++) {
        k_aggregate<<<N_NODES / 16, 128, 0, stream>>>(hsb, row_ptr, csr_src, nd, aggb);
        gemm_ln<<<N_NODES / 64, 256, 0, stream>>>(aggb, Wts[l], bs3[l], ns, hsb);
    }

    // layer 4 (256 -> 1024), bf16 out; LN fused into pool
    k_aggregate<<<N_NODES / 16, 128, 0, stream>>>(hsb, row_ptr, csr_src, nd, aggb);
    gemm_mfma<true, true, false><<<dim3(N_NODES / 128, 8), 256, 0, stream>>>(
        aggb, W4t, b4, nullptr, h4b, nullptr, N_NODES, 1024, 256);

    // per-node LN + mean pool + final LN -> bf16
    k_lnpool<<<dim3(8, 128), 256, 0, stream>>>(h4b, partial);
    k_pool_final<<<128, 256, 0, stream>>>(partial, pooledb);

    // both heads in one GEMM: Bt = [Wmt ; Wst] (contiguous), N=2048, split outputs
    gemm_mfma<false, false, true><<<dim3(1, 16), 256, 0, stream>>>(
        pooledb, Wmt, bm, bsd, out, out + 128 * 1024, 128, 2048, 1024);
}

// Round 6
// 395.026 us; speedup vs baseline: 1.0838x; 1.0838x over previous
//
#include <hip/hip_runtime.h>

#define N_NODES 32768
#define N_EDGES 524288

typedef __attribute__((ext_vector_type(8))) short short8;
typedef __attribute__((ext_vector_type(4))) float floatx4;

#define GLOBAL_AS __attribute__((address_space(1)))
#define LDS_AS __attribute__((address_space(3)))

__device__ __forceinline__ unsigned short f2bf(float x) {
    union { float f; unsigned u; } v; v.f = x;
    unsigned r = v.u + 0x7FFF + ((v.u >> 16) & 1);
    return (unsigned short)(r >> 16);
}
__device__ __forceinline__ float bf2f(unsigned short u) {
    union { unsigned u; float f; } v; v.u = ((unsigned)u) << 16;
    return v.f;
}

// ================================================================ graph preprocessing
// Atomic-free CSR build (round 7): LDS byte histograms -> dense -> prefix -> place.

__global__ __launch_bounds__(256) void k_hist(const int* __restrict__ src,
                                              const int* __restrict__ dst,
                                              unsigned int* __restrict__ histOut32,
                                              unsigned int* __restrict__ histIn32) {
    __shared__ unsigned int hOut[8192];
    __shared__ unsigned int hIn[8192];
    int t = threadIdx.x, b = blockIdx.x;
    for (int i = t; i < 8192; i += 256) { hOut[i] = 0; hIn[i] = 0; }
    __syncthreads();
    int base = b * 4096;
    for (int i = t; i < 4096; i += 256) {
        int s = src[base + i], d = dst[base + i];
        atomicAdd(&hOut[s >> 2], 1u << ((s & 3) * 8));
        atomicAdd(&hIn[d >> 2], 1u << ((d & 3) * 8));
    }
    __syncthreads();
    for (int i = t; i < 8192; i += 256) {
        histOut32[b * 8192 + i] = hOut[i];
        histIn32[b * 8192 + i] = hIn[i];
    }
}

__global__ __launch_bounds__(256) void k_merge(const unsigned int* __restrict__ histOut32,
                                               const unsigned int* __restrict__ histIn32,
                                               unsigned int* __restrict__ pre32,
                                               int* __restrict__ in_deg,
                                               float* __restrict__ ns,
                                               float* __restrict__ nd) {
    int g = blockIdx.x * 256 + threadIdx.x;
    int ri0 = 0, ri1 = 0, ri2 = 0, ri3 = 0;
    for (int b = 0; b < 128; b++) {
        pre32[b * 8192 + g] = (unsigned)ri0 | ((unsigned)ri1 << 8) |
                              ((unsigned)ri2 << 16) | ((unsigned)ri3 << 24);
        unsigned int v = histIn32[b * 8192 + g];
        ri0 += v & 255; ri1 += (v >> 8) & 255; ri2 += (v >> 16) & 255; ri3 += (v >> 24) & 255;
    }
    in_deg[g * 4 + 0] = ri0; in_deg[g * 4 + 1] = ri1;
    in_deg[g * 4 + 2] = ri2; in_deg[g * 4 + 3] = ri3;
    nd[g * 4 + 0] = ri0 > 0 ? rsqrtf((float)ri0) : 1.0f;
    nd[g * 4 + 1] = ri1 > 0 ? rsqrtf((float)ri1) : 1.0f;
    nd[g * 4 + 2] = ri2 > 0 ? rsqrtf((float)ri2) : 1.0f;
    nd[g * 4 + 3] = ri3 > 0 ? rsqrtf((float)ri3) : 1.0f;
    int ro0 = 0, ro1 = 0, ro2 = 0, ro3 = 0;
    for (int b = 0; b < 128; b++) {
        unsigned int v = histOut32[b * 8192 + g];
        ro0 += v & 255; ro1 += (v >> 8) & 255; ro2 += (v >> 16) & 255; ro3 += (v >> 24) & 255;
    }
    ns[g * 4 + 0] = ro0 > 0 ? rsqrtf((float)ro0) : 1.0f;
    ns[g * 4 + 1] = ro1 > 0 ? rsqrtf((float)ro1) : 1.0f;
    ns[g * 4 + 2] = ro2 > 0 ? rsqrtf((float)ro2) : 1.0f;
    ns[g * 4 + 3] = ro3 > 0 ? rsqrtf((float)ro3) : 1.0f;
}

__global__ void k_scan(const int* __restrict__ in_deg, int* __restrict__ row_ptr) {
    __shared__ int part[1024];
    int t = threadIdx.x;
    int base = t * 32;
    int local[32];
    int s = 0;
    for (int i = 0; i < 32; i++) { local[i] = s; s += in_deg[base + i]; }
    part[t] = s;
    __syncthreads();
    for (int off = 1; off < 1024; off <<= 1) {
        int v = (t >= off) ? part[t - off] : 0;
        __syncthreads();
        part[t] += v;
        __syncthreads();
    }
    int prev = (t == 0) ? 0 : part[t - 1];
    for (int i = 0; i < 32; i++) row_ptr[base + i] = prev + local[i];
    if (t == 1023) row_ptr[N_NODES] = part[1023];
}

__global__ __launch_bounds__(256) void k_place(const int* __restrict__ src,
                                               const int* __restrict__ dst,
                                               const unsigned int* __restrict__ pre32,
                                               const int* __restrict__ row_ptr,
                                               int* __restrict__ csr_src) {
    __shared__ unsigned int cur[8192];
    int t = threadIdx.x, b = blockIdx.x;
    for (int i = t; i < 8192; i += 256) cur[i] = 0;
    __syncthreads();
    int base = b * 4096;
    const unsigned int* preb = pre32 + b * 8192;
    for (int i = t; i < 4096; i += 256) {
        int s = src[base + i], d = dst[base + i];
        int sh = (d & 3) * 8;
        unsigned int old = atomicAdd(&cur[d >> 2], 1u << sh);
        int rank = (old >> sh) & 255;
        int pb = (preb[d >> 2] >> sh) & 255;
        csr_src[row_ptr[d] + pb + rank] = s;
    }
}

// ---------------------------------------------- all 6 weight transposes in ONE kernel
struct TransDescs {
    const float* W[6];
    unsigned short* Wt[6];
    int K[6], N[6];
    int end[6];
};

__global__ __launch_bounds__(256) void k_transpose_all(TransDescs d) {
    int id = blockIdx.x, s = 0;
#pragma unroll
    for (int i = 0; i < 6; i++) if (id >= d.end[i]) s = i + 1;
    int base = (s == 0) ? 0 : d.end[s - 1];
    int t = id - base;
    int K = d.K[s], N = d.N[s];
    int ncols = N >> 5;
    int n0 = (t % ncols) * 32, k0 = (t / ncols) * 32;
    const float* W = d.W[s];
    unsigned short* Wt = d.Wt[s];
    __shared__ float tile[32][33];
    int tx = threadIdx.x & 31, ty = threadIdx.x >> 5;
    for (int r = 0; r < 32; r += 8)
        tile[ty + r][tx] = W[(size_t)(k0 + ty + r) * N + n0 + tx];
    __syncthreads();
    for (int r = 0; r < 32; r += 8)
        Wt[(size_t)(n0 + ty + r) * K + k0 + tx] = f2bf(tile[tx][ty + r]);
}

// ---------------------------------------------- x * ns[node] -> CHUNK-MAJOR bf16 table
// Gather table layout: 4 slabs of [N_NODES][64 feats] (4 MiB each == one XCD L2).
// Address of (node n, feat f) in shorts: (f>>6)*(N_NODES*64) + n*64 + (f&63).
__global__ __launch_bounds__(256) void k_scale_x(const float* __restrict__ x,
                                                 const float* __restrict__ ns,
                                                 unsigned short* __restrict__ xsb) {
    int i = blockIdx.x * 256 + threadIdx.x;  // float4 index
    float4 v = ((const float4*)x)[i];
    int n = i >> 6;           // 64 float4 per node
    int f = (i & 63) * 4;     // feature offset (multiple of 4)
    float sc = ns[n];
    ushort4 o;
    o.x = f2bf(v.x * sc); o.y = f2bf(v.y * sc);
    o.z = f2bf(v.z * sc); o.w = f2bf(v.w * sc);
    size_t off = (size_t)(f >> 6) * (N_NODES * 64) + (size_t)n * 64 + (f & 63);
    *(ushort4*)(xsb + off) = o;
}

// ------------------------------------------------ aggregation (gather, CSR by dst)
// Proven ~24us: thread = (node, 16B window), 8-edge unroll, 128-thread blocks,
// 16 blocks/CU. NT short8 stores are FULL-LINE (8 threads x 16B contiguous) ->
// safe streaming; regular-stored aggb was shown (r3) to slow the consumer +11us.
__global__ __launch_bounds__(128, 8) void k_aggregate(
        const unsigned short* __restrict__ hs,   // chunk-major [4][N_NODES][64]
        const int* __restrict__ row_ptr,
        const int* __restrict__ csr_src,
        const float* __restrict__ nd,
        unsigned short* __restrict__ aggb) {     // row-major [N_NODES][256]
    __shared__ int eIdx[512];
    __shared__ int rp[17];
    const int tid = threadIdx.x;
    const int n0 = blockIdx.x * 16;
    if (tid <= 16) rp[tid] = row_ptr[n0 + tid];
    __syncthreads();
    const int ebeg = rp[0];
    const int ecount = rp[16] - ebeg;
    const int ecached = ecount < 512 ? ecount : 512;
    for (int i = tid; i < ecached; i += 128) eIdx[i] = csr_src[ebeg + i];
    __syncthreads();

    const int nl = tid >> 3;     // node local 0..15
    const int fs = tid & 7;      // 16B window within 64-feat chunk
    const int n = n0 + nl;
    const int beg = rp[nl] - ebeg, end = rp[nl + 1] - ebeg;
    const float sc = nd[n];

    auto sweep = [&](auto fetch) {
        for (int c = 0; c < 4; c++) {
            const unsigned short* hp = hs + (size_t)c * (N_NODES * 64) + fs * 8;
            float acc[8];
#pragma unroll
            for (int k = 0; k < 8; k++) acc[k] = 0.f;
            int e = beg;
            for (; e + 8 <= end; e += 8) {
                int s0 = fetch(e),     s1 = fetch(e + 1), s2 = fetch(e + 2), s3 = fetch(e + 3);
                int s4 = fetch(e + 4), s5 = fetch(e + 5), s6 = fetch(e + 6), s7 = fetch(e + 7);
                short8 v0 = *(const short8*)(hp + (size_t)s0 * 64);
                short8 v1 = *(const short8*)(hp + (size_t)s1 * 64);
                short8 v2 = *(const short8*)(hp + (size_t)s2 * 64);
                short8 v3 = *(const short8*)(hp + (size_t)s3 * 64);
                short8 v4 = *(const short8*)(hp + (size_t)s4 * 64);
                short8 v5 = *(const short8*)(hp + (size_t)s5 * 64);
                short8 v6 = *(const short8*)(hp + (size_t)s6 * 64);
                short8 v7 = *(const short8*)(hp + (size_t)s7 * 64);
#pragma unroll
                for (int k = 0; k < 8; k++)
                    acc[k] += ((bf2f((unsigned short)v0[k]) + bf2f((unsigned short)v1[k])) +
                               (bf2f((unsigned short)v2[k]) + bf2f((unsigned short)v3[k]))) +
                              ((bf2f((unsigned short)v4[k]) + bf2f((unsigned short)v5[k])) +
                               (bf2f((unsigned short)v6[k]) + bf2f((unsigned short)v7[k])));
            }
            for (; e + 2 <= end; e += 2) {
                int s0 = fetch(e), s1 = fetch(e + 1);
                short8 v0 = *(const short8*)(hp + (size_t)s0 * 64);
                short8 v1 = *(const short8*)(hp + (size_t)s1 * 64);
#pragma unroll
                for (int k = 0; k < 8; k++)
                    acc[k] += bf2f((unsigned short)v0[k]) + bf2f((unsigned short)v1[k]);
            }
            if (e < end) {
                int s = fetch(e);
                short8 v = *(const short8*)(hp + (size_t)s * 64);
#pragma unroll
                for (int k = 0; k < 8; k++) acc[k] += bf2f((unsigned short)v[k]);
            }
            short8 o;
#pragma unroll
            for (int k = 0; k < 8; k++) o[k] = (short)f2bf(acc[k] * sc);
            __builtin_nontemporal_store(o, (short8*)(aggb + (size_t)n * 256 + c * 64 + fs * 8));
        }
    };
    if (ecount <= 512)
        sweep([&](int e) { return eIdx[e]; });           // hot path: LDS-only indices
    else
        sweep([&](int e) { return csr_src[ebeg + e]; }); // ~never: correctness fallback
}

// ------------------------------------------------ fused 256-wide GEMM + leaky + LN + *ns
// 64-row tiles (grid 512 = 2 blocks/CU). Epilogue: REGULAR stores (r5 lesson:
// NT on 2-byte scattered stores = partial-line write amplification, ~+8us).
__global__ __launch_bounds__(256, 2) void gemm_ln(
        const unsigned short* __restrict__ A, const unsigned short* __restrict__ Bt,
        const float* __restrict__ bias, const float* __restrict__ ns,
        unsigned short* __restrict__ hsb) {
    __shared__ __align__(16) unsigned short As[2][64 * 32];
    __shared__ __align__(16) unsigned short Bs[2][256 * 32];
    __shared__ float sSum[2][64], sSum2[2][64], sMa[64], sMb[64];
    const int tid = threadIdx.x;
    const int lane = tid & 63;
    const int w = tid >> 6;
    const int wr = (w >> 1) * 32;
    const int wc = (w & 1) * 128;
    const int rowBase = blockIdx.x * 64;
    const int K = 256;

    floatx4 acc[2][8];
#pragma unroll
    for (int i = 0; i < 2; i++)
#pragma unroll
        for (int j = 0; j < 8; j++) acc[i][j] = (floatx4){0.f, 0.f, 0.f, 0.f};

    const int pr = lane >> 3;
    const int uu = (lane & 7) ^ pr;
    const int rowInGrp = pr * 2 + (uu >> 2);
    const int kc = (uu & 3) * 8;
    const unsigned short* gA = A + (size_t)(rowBase + w * 16 + rowInGrp) * K + kc;
    const unsigned short* gB = Bt + (size_t)(w * 64 + rowInGrp) * K + kc;
    const int aBase = (w * 16) * 32;
    const int bBase = (w * 64) * 32;

    const int q = lane >> 4;
    const int ln = lane & 15;
    const int uf = (((ln & 1) << 2) | q) ^ ((ln >> 1) & 7);

#define STAGE(buf_, koff_)                                                               \
    {                                                                                    \
        unsigned short* lA = As[buf_] + aBase;                                           \
        unsigned short* lB = Bs[buf_] + bBase;                                           \
        __builtin_amdgcn_global_load_lds((const GLOBAL_AS short*)(gA + (koff_)),         \
                                         (LDS_AS short*)lA, 16, 0, 0);                   \
        __builtin_amdgcn_global_load_lds((const GLOBAL_AS short*)(gB + (koff_)),         \
                                         (LDS_AS short*)lB, 16, 0, 0);                   \
        __builtin_amdgcn_global_load_lds((const GLOBAL_AS short*)(gB + (koff_) + (size_t)16 * K), \
                                         (LDS_AS short*)(lB + 16 * 32), 16, 0, 0);       \
        __builtin_amdgcn_global_load_lds((const GLOBAL_AS short*)(gB + (koff_) + (size_t)32 * K), \
                                         (LDS_AS short*)(lB + 32 * 32), 16, 0, 0);       \
        __builtin_amdgcn_global_load_lds((const GLOBAL_AS short*)(gB + (koff_) + (size_t)48 * K), \
                                         (LDS_AS short*)(lB + 48 * 32), 16, 0, 0);       \
    }

    STAGE(0, 0)
    int buf = 0;
    for (int k0 = 0; k0 < K; k0 += 32) {
        __syncthreads();
        if (k0 + 32 < K) STAGE(buf ^ 1, k0 + 32)
        const unsigned short* rA = As[buf];
        const unsigned short* rB = Bs[buf];
        short8 af[2], bfr[8];
#pragma unroll
        for (int i = 0; i < 2; i++)
            af[i] = *(const short8*)(rA + (((wr + i * 16 + ln) >> 1) << 6) + uf * 8);
#pragma unroll
        for (int j = 0; j < 8; j++)
            bfr[j] = *(const short8*)(rB + (((wc + j * 16 + ln) >> 1) << 6) + uf * 8);
#pragma unroll
        for (int i = 0; i < 2; i++)
#pragma unroll
            for (int j = 0; j < 8; j++)
                acc[i][j] = __builtin_amdgcn_mfma_f32_16x16x32_bf16(af[i], bfr[j], acc[i][j], 0, 0, 0);
        buf ^= 1;
    }
#undef STAGE

    float bcol[8];
#pragma unroll
    for (int j = 0; j < 8; j++) bcol[j] = bias[wc + j * 16 + ln];
    const int wcIdx = w & 1;
#pragma unroll
    for (int i = 0; i < 2; i++) {
#pragma unroll
        for (int r = 0; r < 4; r++) {
            float s = 0.f, s2 = 0.f;
#pragma unroll
            for (int j = 0; j < 8; j++) {
                float v = acc[i][j][r] + bcol[j];
                v = v >= 0.f ? v : 0.01f * v;
                s += v; s2 += v * v;
            }
#pragma unroll
            for (int off = 8; off > 0; off >>= 1) {
                s += __shfl_down(s, off, 16);
                s2 += __shfl_down(s2, off, 16);
            }
            if (ln == 0) {
                int row = wr + i * 16 + q * 4 + r;
                sSum[wcIdx][row] = s;
                sSum2[wcIdx][row] = s2;
            }
        }
    }
    __syncthreads();
    if (tid < 64) {
        float mu = (sSum[0][tid] + sSum[1][tid]) * (1.0f / 256.0f);
        float var = (sSum2[0][tid] + sSum2[1][tid]) * (1.0f / 256.0f) - mu * mu;
        float rs = rsqrtf(var + 1e-5f);
        float nsv = ns[rowBase + tid];
        sMa[tid] = rs * nsv;
        sMb[tid] = -mu * rs * nsv;
    }
    __syncthreads();
#pragma unroll
    for (int i = 0; i < 2; i++) {
#pragma unroll
        for (int r = 0; r < 4; r++) {
            int row = wr + i * 16 + q * 4 + r;
            float a = sMa[row], bb = sMb[row];
#pragma unroll
            for (int j = 0; j < 8; j++) {
                float v = acc[i][j][r] + bcol[j];
                v = v >= 0.f ? v : 0.01f * v;
                int col = wc + j * 16 + ln;
                size_t off = (size_t)(col >> 6) * (N_NODES * 64) +
                             (size_t)(rowBase + row) * 64 + (col & 63);
                hsb[off] = f2bf(v * a + bb);
            }
        }
    }
}

// ------------------------------------------------ bf16 MFMA GEMM (layer 4)
// Regular OUT stores (r5 lesson: NT 2-byte scattered -> 1.85x write amplification).
template <bool LEAKY, bool OUT_BF16>
__global__ __launch_bounds__(256) void gemm_mfma(
        const unsigned short* __restrict__ A, const unsigned short* __restrict__ Bt,
        const float* __restrict__ bias,
        void* __restrict__ Cv,
        int M, int N, int K) {
    __shared__ __align__(16) unsigned short As[2][128 * 32];
    __shared__ __align__(16) unsigned short Bs[2][128 * 32];
    const int tid = threadIdx.x;
    const int lane = tid & 63;
    const int w = tid >> 6;
    const int wr = (w >> 1) * 64;
    const int wc = (w & 1) * 64;
    const int rowBase = blockIdx.x * 128;
    const int colBase = blockIdx.y * 128;

    floatx4 acc[4][4];
#pragma unroll
    for (int i = 0; i < 4; i++)
#pragma unroll
        for (int j = 0; j < 4; j++) acc[i][j] = (floatx4){0.f, 0.f, 0.f, 0.f};

    const int pr = lane >> 3;
    const int uu = (lane & 7) ^ pr;
    const int srow = w * 32 + pr * 2 + (uu >> 2);
    const int kc = (uu & 3) * 8;
    const unsigned short* gA = A + (size_t)(rowBase + srow) * K + kc;
    const unsigned short* gB = Bt + (size_t)(colBase + srow) * K + kc;
    const int wbase = (w * 32) * 32;

    const int q = lane >> 4;
    const int ln = lane & 15;
    const int uf = (((ln & 1) << 2) | q) ^ ((ln >> 1) & 7);

    {
        unsigned short* lA = As[0] + wbase;
        unsigned short* lB = Bs[0] + wbase;
        __builtin_amdgcn_global_load_lds((const GLOBAL_AS short*)(gA),
                                         (LDS_AS short*)lA, 16, 0, 0);
        __builtin_amdgcn_global_load_lds((const GLOBAL_AS short*)(gA + (size_t)16 * K),
                                         (LDS_AS short*)(lA + 16 * 32), 16, 0, 0);
        __builtin_amdgcn_global_load_lds((const GLOBAL_AS short*)(gB),
                                         (LDS_AS short*)lB, 16, 0, 0);
        __builtin_amdgcn_global_load_lds((const GLOBAL_AS short*)(gB + (size_t)16 * K),
                                         (LDS_AS short*)(lB + 16 * 32), 16, 0, 0);
    }

    int buf = 0;
    for (int k0 = 0; k0 < K; k0 += 32) {
        __syncthreads();
        if (k0 + 32 < K) {
            unsigned short* lA = As[buf ^ 1] + wbase;
            unsigned short* lB = Bs[buf ^ 1] + wbase;
            __builtin_amdgcn_global_load_lds((const GLOBAL_AS short*)(gA + k0 + 32),
                                             (LDS_AS short*)lA, 16, 0, 0);
            __builtin_amdgcn_global_load_lds((const GLOBAL_AS short*)(gA + k0 + 32 + (size_t)16 * K),
                                             (LDS_AS short*)(lA + 16 * 32), 16, 0, 0);
            __builtin_amdgcn_global_load_lds((const GLOBAL_AS short*)(gB + k0 + 32),
                                             (LDS_AS short*)lB, 16, 0, 0);
            __builtin_amdgcn_global_load_lds((const GLOBAL_AS short*)(gB + k0 + 32 + (size_t)16 * K),
                                             (LDS_AS short*)(lB + 16 * 32), 16, 0, 0);
        }
        const unsigned short* rA = As[buf];
        const unsigned short* rB = Bs[buf];
        short8 af[4], bfr[4];
#pragma unroll
        for (int i = 0; i < 4; i++)
            af[i] = *(const short8*)(rA + (((wr + i * 16 + ln) >> 1) << 6) + uf * 8);
#pragma unroll
        for (int j = 0; j < 4; j++)
            bfr[j] = *(const short8*)(rB + (((wc + j * 16 + ln) >> 1) << 6) + uf * 8);
#pragma unroll
        for (int i = 0; i < 4; i++)
#pragma unroll
            for (int j = 0; j < 4; j++)
                acc[i][j] = __builtin_amdgcn_mfma_f32_16x16x32_bf16(af[i], bfr[j], acc[i][j], 0, 0, 0);
        buf ^= 1;
    }
#pragma unroll
    for (int i = 0; i < 4; i++) {
#pragma unroll
        for (int j = 0; j < 4; j++) {
#pragma unroll
            for (int r = 0; r < 4; r++) {
                int row = rowBase + wr + i * 16 + q * 4 + r;
                int col = colBase + wc + j * 16 + ln;
                float v = acc[i][j][r] + bias[col];
                if (LEAKY) v = v >= 0.f ? v : 0.01f * v;
                if (OUT_BF16)
                    ((unsigned short*)Cv)[(size_t)row * N + col] = f2bf(v);
                else
                    ((float*)Cv)[(size_t)row * N + col] = v;
            }
        }
    }
}

// ------------------------------------------------ heads GEMM, K-split x8 -> fp32 partials
// M=128, N=2048, K=1024. grid (16 colTiles, 8 kSlices) = 128 blocks (was 16).
// Each block: 128x128 tile, K-slice of 128 (4 K-iters). Partials reduced by
// k_heads_reduce (adds bias, splits mean/log_std).
__global__ __launch_bounds__(256) void gemm_heads(
        const unsigned short* __restrict__ A,   // pooledb [128][1024] bf16
        const unsigned short* __restrict__ Bt,  // [Wmt;Wst] [2048][1024] bf16
        float* __restrict__ P) {                // [8][128][2048] fp32
    __shared__ __align__(16) unsigned short As[2][128 * 32];
    __shared__ __align__(16) unsigned short Bs[2][128 * 32];
    const int tid = threadIdx.x;
    const int lane = tid & 63;
    const int w = tid >> 6;
    const int wr = (w >> 1) * 64;
    const int wc = (w & 1) * 64;
    const int colBase = blockIdx.x * 128;
    const int ks = blockIdx.y;        // K-slice 0..7
    const int K = 1024;

    floatx4 acc[4][4];
#pragma unroll
    for (int i = 0; i < 4; i++)
#pragma unroll
        for (int j = 0; j < 4; j++) acc[i][j] = (floatx4){0.f, 0.f, 0.f, 0.f};

    const int pr = lane >> 3;
    const int uu = (lane & 7) ^ pr;
    const int srow = w * 32 + pr * 2 + (uu >> 2);
    const int kc = (uu & 3) * 8;
    const unsigned short* gA = A + (size_t)srow * K + ks * 128 + kc;
    const unsigned short* gB = Bt + (size_t)(colBase + srow) * K + ks * 128 + kc;
    const int wbase = (w * 32) * 32;

    const int q = lane >> 4;
    const int ln = lane & 15;
    const int uf = (((ln & 1) << 2) | q) ^ ((ln >> 1) & 7);

    {
        unsigned short* lA = As[0] + wbase;
        unsigned short* lB = Bs[0] + wbase;
        __builtin_amdgcn_global_load_lds((const GLOBAL_AS short*)(gA),
                                         (LDS_AS short*)lA, 16, 0, 0);
        __builtin_amdgcn_global_load_lds((const GLOBAL_AS short*)(gA + (size_t)16 * K),
                                         (LDS_AS short*)(lA + 16 * 32), 16, 0, 0);
        __builtin_amdgcn_global_load_lds((const GLOBAL_AS short*)(gB),
                                         (LDS_AS short*)lB, 16, 0, 0);
        __builtin_amdgcn_global_load_lds((const GLOBAL_AS short*)(gB + (size_t)16 * K),
                                         (LDS_AS short*)(lB + 16 * 32), 16, 0, 0);
    }

    int buf = 0;
    for (int k0 = 0; k0 < 128; k0 += 32) {
        __syncthreads();
        if (k0 + 32 < 128) {
            unsigned short* lA = As[buf ^ 1] + wbase;
            unsigned short* lB = Bs[buf ^ 1] + wbase;
            __builtin_amdgcn_global_load_lds((const GLOBAL_AS short*)(gA + k0 + 32),
                                             (LDS_AS short*)lA, 16, 0, 0);
            __builtin_amdgcn_global_load_lds((const GLOBAL_AS short*)(gA + k0 + 32 + (size_t)16 * K),
                                             (LDS_AS short*)(lA + 16 * 32), 16, 0, 0);
            __builtin_amdgcn_global_load_lds((const GLOBAL_AS short*)(gB + k0 + 32),
                                             (LDS_AS short*)lB, 16, 0, 0);
            __builtin_amdgcn_global_load_lds((const GLOBAL_AS short*)(gB + k0 + 32 + (size_t)16 * K),
                                             (LDS_AS short*)(lB + 16 * 32), 16, 0, 0);
        }
        const unsigned short* rA = As[buf];
        const unsigned short* rB = Bs[buf];
        short8 af[4], bfr[4];
#pragma unroll
        for (int i = 0; i < 4; i++)
            af[i] = *(const short8*)(rA + (((wr + i * 16 + ln) >> 1) << 6) + uf * 8);
#pragma unroll
        for (int j = 0; j < 4; j++)
            bfr[j] = *(const short8*)(rB + (((wc + j * 16 + ln) >> 1) << 6) + uf * 8);
#pragma unroll
        for (int i = 0; i < 4; i++)
#pragma unroll
            for (int j = 0; j < 4; j++)
                acc[i][j] = __builtin_amdgcn_mfma_f32_16x16x32_bf16(af[i], bfr[j], acc[i][j], 0, 0, 0);
        buf ^= 1;
    }
    float* Pk = P + (size_t)ks * 128 * 2048;
#pragma unroll
    for (int i = 0; i < 4; i++) {
#pragma unroll
        for (int j = 0; j < 4; j++) {
#pragma unroll
            for (int r = 0; r < 4; r++) {
                int row = wr + i * 16 + q * 4 + r;
                int col = colBase + wc + j * 16 + ln;
                Pk[(size_t)row * 2048 + col] = acc[i][j][r];
            }
        }
    }
}

__global__ __launch_bounds__(256) void k_heads_reduce(
        const float* __restrict__ P, const float* __restrict__ bm,
        const float* __restrict__ bsd, float* __restrict__ out) {
    int idx = blockIdx.x * 256 + threadIdx.x;  // float4 index, 65536 total
    int row = idx >> 9;                        // 512 float4 per row
    int col = (idx & 511) * 4;
    floatx4 s = (floatx4){0.f, 0.f, 0.f, 0.f};
#pragma unroll
    for (int p = 0; p < 8; p++)
        s += *(const floatx4*)(P + (size_t)p * 128 * 2048 + (size_t)row * 2048 + col);
    bool hi = col >= 1024;
    const float* bias = hi ? bsd : bm;
    int bc = hi ? col - 1024 : col;
    s += *(const floatx4*)(bias + bc);
    float* o = hi ? (out + (size_t)128 * 1024 + (size_t)row * 1024 + bc)
                  : (out + (size_t)row * 1024 + col);
    *(floatx4*)o = s;
}

// ------------------------------------------------ fused per-node LN(1024) + partial mean-pool
__global__ __launch_bounds__(256) void k_lnpool(const unsigned short* __restrict__ h4,
                                                float* __restrict__ partial) {
    const int g = blockIdx.y, p = blockIdx.x;
    const int w = threadIdx.x >> 6, lane = threadIdx.x & 63;
    float acc[16];
#pragma unroll
    for (int k = 0; k < 16; k++) acc[k] = 0.f;
    for (int i = 0; i < 8; i++) {
        int node = (g * 8 + p) * 32 + w * 8 + i;
        const unsigned short* row = h4 + (size_t)node * 1024 + lane * 16;
        short8 a = *(const short8*)row;
        short8 b = *(const short8*)(row + 8);
        float v[16];
#pragma unroll
        for (int k = 0; k < 8; k++) v[k] = bf2f((unsigned short)a[k]);
#pragma unroll
        for (int k = 0; k < 8; k++) v[8 + k] = bf2f((unsigned short)b[k]);
        float s = 0.f, s2 = 0.f;
#pragma unroll
        for (int k = 0; k < 16; k++) { s += v[k]; s2 += v[k] * v[k]; }
#pragma unroll
        for (int off = 32; off > 0; off >>= 1) {
            s += __shfl_down(s, off);
            s2 += __shfl_down(s2, off);
        }
        s = __shfl(s, 0);
        s2 = __shfl(s2, 0);
        float mu = s * (1.0f / 1024.0f);
        float var = s2 * (1.0f / 1024.0f) - mu * mu;
        float rs = rsqrtf(var + 1e-5f);
#pragma unroll
        for (int k = 0; k < 16; k++) acc[k] += (v[k] - mu) * rs;
    }
    __shared__ float red[4][1024];
    float* my = red[w] + lane * 16;
#pragma unroll
    for (int k = 0; k < 16; k++) my[k] = acc[k];
    __syncthreads();
    int t = threadIdx.x;
    floatx4 o = (floatx4){0.f, 0.f, 0.f, 0.f};
#pragma unroll
    for (int w2 = 0; w2 < 4; w2++) {
        const floatx4 v = *(const floatx4*)(red[w2] + t * 4);
        o += v;
    }
    __builtin_nontemporal_store(o, (floatx4*)(partial + (size_t)(g * 8 + p) * 1024 + t * 4));
}

__global__ __launch_bounds__(256) void k_pool_final(const float* __restrict__ partial,
                                                    unsigned short* __restrict__ pooledb) {
    int g = blockIdx.x, t = threadIdx.x;
    int wave = t >> 6;
    float4 a = make_float4(0.f, 0.f, 0.f, 0.f);
    for (int p = 0; p < 8; p++) {
        float4 v = *(const float4*)(partial + (size_t)(g * 8 + p) * 1024 + t * 4);
        a.x += v.x; a.y += v.y; a.z += v.z; a.w += v.w;
    }
    const float invn = 1.0f / 256.0f;
    a.x *= invn; a.y *= invn; a.z *= invn; a.w *= invn;
    float s = a.x + a.y + a.z + a.w;
    float s2 = a.x * a.x + a.y * a.y + a.z * a.z + a.w * a.w;
#pragma unroll
    for (int off = 32; off > 0; off >>= 1) {
        s += __shfl_down(s, off);
        s2 += __shfl_down(s2, off);
    }
    __shared__ float ss[4], ss2[4];
    if ((t & 63) == 0) { ss[wave] = s; ss2[wave] = s2; }
    __syncthreads();
    if (t == 0) {
        float tt = 0.f, tt2 = 0.f;
        for (int w = 0; w < 4; w++) { tt += ss[w]; tt2 += ss2[w]; }
        float mu = tt / 1024.f;
        float var = tt2 / 1024.f - mu * mu;
        ss[0] = mu;
        ss2[0] = rsqrtf(var + 1e-5f);
    }
    __syncthreads();
    float mu = ss[0], inv = ss2[0];
    ushort4 o;
    o.x = f2bf((a.x - mu) * inv); o.y = f2bf((a.y - mu) * inv);
    o.z = f2bf((a.z - mu) * inv); o.w = f2bf((a.w - mu) * inv);
    *(ushort4*)(pooledb + (size_t)g * 1024 + t * 4) = o;
}

// ---------------------------------------------------------------- launch
extern "C" void kernel_launch(void* const* d_in, const int* in_sizes, int n_in,
                              void* d_out, int out_size, void* d_ws, size_t ws_size,
                              hipStream_t stream) {
    const float* x  = (const float*)d_in[0];
    const int*   src = (const int*)d_in[1];
    const int*   dst = (const int*)d_in[2];
    const float* W1 = (const float*)d_in[3];  const float* b1 = (const float*)d_in[4];
    const float* W2 = (const float*)d_in[5];  const float* b2 = (const float*)d_in[6];
    const float* W3 = (const float*)d_in[7];  const float* b3 = (const float*)d_in[8];
    const float* W4 = (const float*)d_in[9];  const float* b4 = (const float*)d_in[10];
    const float* Wm = (const float*)d_in[11]; const float* bm = (const float*)d_in[12];
    const float* Wsd = (const float*)d_in[13]; const float* bsd = (const float*)d_in[14];
    float* out = (float*)d_out;

    char* w = (char*)d_ws;
    unsigned short* aggb = (unsigned short*)w; w += (size_t)N_NODES * 256 * 2;
    unsigned short* hsb  = (unsigned short*)w; w += (size_t)N_NODES * 256 * 2;
    unsigned short* h4b  = (unsigned short*)w; w += (size_t)N_NODES * 1024 * 2;
    float* partial = (float*)w; w += (size_t)128 * 8 * 1024 * 4;
    unsigned short* pooledb = (unsigned short*)w; w += (size_t)128 * 1024 * 2;
    unsigned short* W1t = (unsigned short*)w; w += (size_t)256 * 256 * 2;
    unsigned short* W2t = (unsigned short*)w; w += (size_t)256 * 256 * 2;
    unsigned short* W3t = (unsigned short*)w; w += (size_t)256 * 256 * 2;
    unsigned short* W4t = (unsigned short*)w; w += (size_t)256 * 1024 * 2;
    unsigned short* Wmt = (unsigned short*)w; w += (size_t)1024 * 1024 * 2;  // Wst must follow
    unsigned short* Wst = (unsigned short*)w; w += (size_t)1024 * 1024 * 2;  // contiguous: cat
    float* ns     = (float*)w; w += (size_t)N_NODES * 4;
    float* nd     = (float*)w; w += (size_t)N_NODES * 4;
    unsigned int* histOut32 = (unsigned int*)w; w += (size_t)128 * 8192 * 4;
    unsigned int* histIn32  = (unsigned int*)w; w += (size_t)128 * 8192 * 4;
    unsigned int* pre32     = (unsigned int*)w; w += (size_t)128 * 8192 * 4;
    int* in_deg   = (int*)w;   w += (size_t)N_NODES * 4;
    int* row_ptr  = (int*)w;   w += (size_t)(N_NODES + 1) * 4;
    int* csr_src  = (int*)w;   w += (size_t)N_EDGES * 4;
    // heads partials reuse hist area (dead after k_place): 8 MB needed, 8 MB available
    float* headp = (float*)histOut32;

    // weights (independent of graph work)
    TransDescs td;
    td.W[0] = W1; td.W[1] = W2; td.W[2] = W3; td.W[3] = W4; td.W[4] = Wm; td.W[5] = Wsd;
    td.Wt[0] = W1t; td.Wt[1] = W2t; td.Wt[2] = W3t; td.Wt[3] = W4t; td.Wt[4] = Wmt; td.Wt[5] = Wst;
    td.K[0] = 256; td.K[1] = 256; td.K[2] = 256; td.K[3] = 256; td.K[4] = 1024; td.K[5] = 1024;
    td.N[0] = 256; td.N[1] = 256; td.N[2] = 256; td.N[3] = 1024; td.N[4] = 1024; td.N[5] = 1024;
    td.end[0] = 64; td.end[1] = 128; td.end[2] = 192; td.end[3] = 448; td.end[4] = 1472; td.end[5] = 2496;
    k_transpose_all<<<2496, 256, 0, stream>>>(td);

    // atomic-free graph preprocessing
    k_hist<<<128, 256, 0, stream>>>(src, dst, histOut32, histIn32);
    k_merge<<<32, 256, 0, stream>>>(histOut32, histIn32, pre32, in_deg, ns, nd);
    k_scan<<<1, 1024, 0, stream>>>(in_deg, row_ptr);
    k_place<<<128, 256, 0, stream>>>(src, dst, pre32, row_ptr, csr_src);

    // layer-1 gather table: x * ns -> bf16 (chunk-major slabs)
    k_scale_x<<<N_NODES * 256 / 1024, 256, 0, stream>>>(x, ns, hsb);

    // layers 1-3: high-occupancy aggregate -> fused GEMM+leaky+LN+*ns -> chunk-major table
    const unsigned short* Wts[3] = {W1t, W2t, W3t};
    const float* bs3[3] = {b1, b2, b3};
    for (int l = 0; l < 3; l++) {
        k_aggregate<<<N_NODES / 16, 128, 0, stream>>>(hsb, row_ptr, csr_src, nd, aggb);
        gemm_ln<<<N_NODES / 64, 256, 0, stream>>>(aggb, Wts[l], bs3[l], ns, hsb);
    }

    // layer 4 (256 -> 1024), bf16 out; LN fused into pool
    k_aggregate<<<N_NODES / 16, 128, 0, stream>>>(hsb, row_ptr, csr_src, nd, aggb);
    gemm_mfma<true, true><<<dim3(N_NODES / 128, 8), 256, 0, stream>>>(
        aggb, W4t, b4, h4b, N_NODES, 1024, 256);

    // per-node LN + mean pool + final LN -> bf16
    k_lnpool<<<dim3(8, 128), 256, 0, stream>>>(h4b, partial);
    k_pool_final<<<128, 256, 0, stream>>>(partial, pooledb);

    // heads: K-split x8 GEMM (128 blocks) -> fp32 partials -> reduce+bias+split
    gemm_heads<<<dim3(16, 8), 256, 0, stream>>>(pooledb, Wmt, headp);
    k_heads_reduce<<<256, 256, 0, stream>>>(headp, bm, bsd, out);
}

// Round 7
// 363.497 us; speedup vs baseline: 1.1778x; 1.0867x over previous
//
#include <hip/hip_runtime.h>

#define N_NODES 32768
#define N_EDGES 524288

typedef __attribute__((ext_vector_type(8))) short short8;
typedef __attribute__((ext_vector_type(4))) float floatx4;

#define GLOBAL_AS __attribute__((address_space(1)))
#define LDS_AS __attribute__((address_space(3)))

__device__ __forceinline__ unsigned short f2bf(float x) {
    union { float f; unsigned u; } v; v.f = x;
    unsigned r = v.u + 0x7FFF + ((v.u >> 16) & 1);
    return (unsigned short)(r >> 16);
}
__device__ __forceinline__ float bf2f(unsigned short u) {
    union { unsigned u; float f; } v; v.u = ((unsigned)u) << 16;
    return v.f;
}

// ================================================================ graph preprocessing
// Atomic-free CSR build: LDS byte histograms -> dense -> prefix -> place.

__global__ __launch_bounds__(256) void k_hist(const int* __restrict__ src,
                                              const int* __restrict__ dst,
                                              unsigned int* __restrict__ histOut32,
                                              unsigned int* __restrict__ histIn32) {
    __shared__ unsigned int hOut[8192];
    __shared__ unsigned int hIn[8192];
    int t = threadIdx.x, b = blockIdx.x;
    for (int i = t; i < 8192; i += 256) { hOut[i] = 0; hIn[i] = 0; }
    __syncthreads();
    int base = b * 4096;
    for (int i = t; i < 4096; i += 256) {
        int s = src[base + i], d = dst[base + i];
        atomicAdd(&hOut[s >> 2], 1u << ((s & 3) * 8));
        atomicAdd(&hIn[d >> 2], 1u << ((d & 3) * 8));
    }
    __syncthreads();
    for (int i = t; i < 8192; i += 256) {
        histOut32[b * 8192 + i] = hOut[i];
        histIn32[b * 8192 + i] = hIn[i];
    }
}

__global__ __launch_bounds__(256) void k_merge(const unsigned int* __restrict__ histOut32,
                                               const unsigned int* __restrict__ histIn32,
                                               unsigned int* __restrict__ pre32,
                                               int* __restrict__ in_deg,
                                               float* __restrict__ ns,
                                               float* __restrict__ nd) {
    int g = blockIdx.x * 256 + threadIdx.x;
    int ri0 = 0, ri1 = 0, ri2 = 0, ri3 = 0;
    for (int b = 0; b < 128; b++) {
        pre32[b * 8192 + g] = (unsigned)ri0 | ((unsigned)ri1 << 8) |
                              ((unsigned)ri2 << 16) | ((unsigned)ri3 << 24);
        unsigned int v = histIn32[b * 8192 + g];
        ri0 += v & 255; ri1 += (v >> 8) & 255; ri2 += (v >> 16) & 255; ri3 += (v >> 24) & 255;
    }
    in_deg[g * 4 + 0] = ri0; in_deg[g * 4 + 1] = ri1;
    in_deg[g * 4 + 2] = ri2; in_deg[g * 4 + 3] = ri3;
    nd[g * 4 + 0] = ri0 > 0 ? rsqrtf((float)ri0) : 1.0f;
    nd[g * 4 + 1] = ri1 > 0 ? rsqrtf((float)ri1) : 1.0f;
    nd[g * 4 + 2] = ri2 > 0 ? rsqrtf((float)ri2) : 1.0f;
    nd[g * 4 + 3] = ri3 > 0 ? rsqrtf((float)ri3) : 1.0f;
    int ro0 = 0, ro1 = 0, ro2 = 0, ro3 = 0;
    for (int b = 0; b < 128; b++) {
        unsigned int v = histOut32[b * 8192 + g];
        ro0 += v & 255; ro1 += (v >> 8) & 255; ro2 += (v >> 16) & 255; ro3 += (v >> 24) & 255;
    }
    ns[g * 4 + 0] = ro0 > 0 ? rsqrtf((float)ro0) : 1.0f;
    ns[g * 4 + 1] = ro1 > 0 ? rsqrtf((float)ro1) : 1.0f;
    ns[g * 4 + 2] = ro2 > 0 ? rsqrtf((float)ro2) : 1.0f;
    ns[g * 4 + 3] = ro3 > 0 ? rsqrtf((float)ro3) : 1.0f;
}

__global__ void k_scan(const int* __restrict__ in_deg, int* __restrict__ row_ptr) {
    __shared__ int part[1024];
    int t = threadIdx.x;
    int base = t * 32;
    int local[32];
    int s = 0;
    for (int i = 0; i < 32; i++) { local[i] = s; s += in_deg[base + i]; }
    part[t] = s;
    __syncthreads();
    for (int off = 1; off < 1024; off <<= 1) {
        int v = (t >= off) ? part[t - off] : 0;
        __syncthreads();
        part[t] += v;
        __syncthreads();
    }
    int prev = (t == 0) ? 0 : part[t - 1];
    for (int i = 0; i < 32; i++) row_ptr[base + i] = prev + local[i];
    if (t == 1023) row_ptr[N_NODES] = part[1023];
}

__global__ __launch_bounds__(256) void k_place(const int* __restrict__ src,
                                               const int* __restrict__ dst,
                                               const unsigned int* __restrict__ pre32,
                                               const int* __restrict__ row_ptr,
                                               int* __restrict__ csr_src) {
    __shared__ unsigned int cur[8192];
    int t = threadIdx.x, b = blockIdx.x;
    for (int i = t; i < 8192; i += 256) cur[i] = 0;
    __syncthreads();
    int base = b * 4096;
    const unsigned int* preb = pre32 + b * 8192;
    for (int i = t; i < 4096; i += 256) {
        int s = src[base + i], d = dst[base + i];
        int sh = (d & 3) * 8;
        unsigned int old = atomicAdd(&cur[d >> 2], 1u << sh);
        int rank = (old >> sh) & 255;
        int pb = (preb[d >> 2] >> sh) & 255;
        csr_src[row_ptr[d] + pb + rank] = s;
    }
}

// ---------------------------------------------- all 6 weight transposes in ONE kernel
struct TransDescs {
    const float* W[6];
    unsigned short* Wt[6];
    int K[6], N[6];
    int end[6];
};

__global__ __launch_bounds__(256) void k_transpose_all(TransDescs d) {
    int id = blockIdx.x, s = 0;
#pragma unroll
    for (int i = 0; i < 6; i++) if (id >= d.end[i]) s = i + 1;
    int base = (s == 0) ? 0 : d.end[s - 1];
    int t = id - base;
    int K = d.K[s], N = d.N[s];
    int ncols = N >> 5;
    int n0 = (t % ncols) * 32, k0 = (t / ncols) * 32;
    const float* W = d.W[s];
    unsigned short* Wt = d.Wt[s];
    __shared__ float tile[32][33];
    int tx = threadIdx.x & 31, ty = threadIdx.x >> 5;
    for (int r = 0; r < 32; r += 8)
        tile[ty + r][tx] = W[(size_t)(k0 + ty + r) * N + n0 + tx];
    __syncthreads();
    for (int r = 0; r < 32; r += 8)
        Wt[(size_t)(n0 + ty + r) * K + k0 + tx] = f2bf(tile[tx][ty + r]);
}

// ---------------------------------------------- x * ns[node] -> CHUNK-MAJOR bf16 table
// Table layout: 4 slabs of [N_NODES][64 feats].
__global__ __launch_bounds__(256) void k_scale_x(const float* __restrict__ x,
                                                 const float* __restrict__ ns,
                                                 unsigned short* __restrict__ xsb) {
    int i = blockIdx.x * 256 + threadIdx.x;  // float4 index
    float4 v = ((const float4*)x)[i];
    int n = i >> 6;           // 64 float4 per node
    int f = (i & 63) * 4;     // feature offset (multiple of 4)
    float sc = ns[n];
    ushort4 o;
    o.x = f2bf(v.x * sc); o.y = f2bf(v.y * sc);
    o.z = f2bf(v.z * sc); o.w = f2bf(v.w * sc);
    size_t off = (size_t)(f >> 6) * (N_NODES * 64) + (size_t)n * 64 + (f & 63);
    *(ushort4*)(xsb + off) = o;
}

// ================================================================ FUSED layer (1-3)
// Block = 64 output nodes, 512 threads, 2 blocks/CU.
// Phase 1: gather-aggregate the 64x256 A-tile straight into LDS, written in the
//   MFMA pair-swizzled layout (mirrors global_load_lds's lane mapping): element
//   (r,k) -> At[(k>>5)*2048 + (r>>1)*64 + ((((r&1)<<2)|((k>>3)&3))^((r>>1)&7))*8 + (k&7)].
// Phase 2: K-loop MFMA from At (LDS) x Bt (global_load_lds double-buffered; first
//   B-stage issued BEFORE the gather so it flies underneath).
// Phase 3: LN epilogue (+ *ns) -> chunk-major output table (ping-pong buffer).
// Wins: kills the aggb 16MB write+read and a launch gap per layer; gather and
// MFMA phases of co-resident blocks overlap on disjoint pipes.
__global__ __launch_bounds__(512, 4) void fused_layer(
        const unsigned short* __restrict__ hs,   // in table, chunk-major [4][N][64]
        const int* __restrict__ row_ptr,
        const int* __restrict__ csr_src,
        const float* __restrict__ nd,
        const unsigned short* __restrict__ Bt,   // [256][256] bf16 (N x K)
        const float* __restrict__ bias,
        const float* __restrict__ ns,
        unsigned short* __restrict__ ho) {       // out table, chunk-major [4][N][64]
    __shared__ __align__(16) unsigned short At[8 * 2048];   // 32 KB
    __shared__ __align__(16) unsigned short Bs[2][256 * 32]; // 32 KB
    __shared__ int eIdx[2048];                               // 8 KB (+32 sigma)
    __shared__ int rp[65];
    __shared__ float sSum[4][64], sSum2[4][64], sMa[64], sMb[64];
    const int tid = threadIdx.x;
    const int lane = tid & 63;
    const int w = tid >> 6;            // wave 0..7
    const int n0 = blockIdx.x * 64;
    const int K = 256;

    // B-staging geometry (identical lane mapping to the proven GEMMs)
    const int pr = lane >> 3;
    const int uu = (lane & 7) ^ pr;
    const int rowInGrp = pr * 2 + (uu >> 2);
    const int kc = (uu & 3) * 8;
    const unsigned short* gB = Bt + (size_t)(w * 32 + rowInGrp) * K + kc;
    const int bBase = (w * 32) * 32;
#define STAGEB(buf_, koff_)                                                              \
    {                                                                                    \
        unsigned short* lB = Bs[buf_] + bBase;                                           \
        __builtin_amdgcn_global_load_lds((const GLOBAL_AS short*)(gB + (koff_)),         \
                                         (LDS_AS short*)lB, 16, 0, 0);                   \
        __builtin_amdgcn_global_load_lds((const GLOBAL_AS short*)(gB + (koff_) + (size_t)16 * K), \
                                         (LDS_AS short*)(lB + 16 * 32), 16, 0, 0);       \
    }
    STAGEB(0, 0)   // in flight during the whole gather phase

    if (tid <= 64) rp[tid] = row_ptr[n0 + tid];
    __syncthreads();
    const int ebeg = rp[0];
    const int ecount = rp[64] - ebeg;
    const int ecached = ecount < 2048 ? ecount : 2048;
    for (int i = tid; i < ecached; i += 512) eIdx[i] = csr_src[ebeg + i];
    __syncthreads();

    // ---- phase 1: gather. thread = (node r, 16B window fs); 1 task/thread/chunk.
    const int r = tid >> 3;           // 0..63
    const int fs = tid & 7;           // 16B window within 64-feat chunk
    const int beg = rp[r] - ebeg, end = rp[r + 1] - ebeg;
    const float sc = nd[n0 + r];
    const int rowpair = r >> 1;
    unsigned short* atp = At + rowpair * 64 +
                          (((((r & 1) << 2) | (fs & 3)) ^ (rowpair & 7)) << 3);

    auto sweep = [&](auto fetch) {
        for (int c = 0; c < 4; c++) {
            const unsigned short* hp = hs + (size_t)c * (N_NODES * 64) + fs * 8;
            float acc[8];
#pragma unroll
            for (int k = 0; k < 8; k++) acc[k] = 0.f;
            int e = beg;
            for (; e + 8 <= end; e += 8) {
                int s0 = fetch(e),     s1 = fetch(e + 1), s2 = fetch(e + 2), s3 = fetch(e + 3);
                int s4 = fetch(e + 4), s5 = fetch(e + 5), s6 = fetch(e + 6), s7 = fetch(e + 7);
                short8 v0 = *(const short8*)(hp + (size_t)s0 * 64);
                short8 v1 = *(const short8*)(hp + (size_t)s1 * 64);
                short8 v2 = *(const short8*)(hp + (size_t)s2 * 64);
                short8 v3 = *(const short8*)(hp + (size_t)s3 * 64);
                short8 v4 = *(const short8*)(hp + (size_t)s4 * 64);
                short8 v5 = *(const short8*)(hp + (size_t)s5 * 64);
                short8 v6 = *(const short8*)(hp + (size_t)s6 * 64);
                short8 v7 = *(const short8*)(hp + (size_t)s7 * 64);
#pragma unroll
                for (int k = 0; k < 8; k++)
                    acc[k] += ((bf2f((unsigned short)v0[k]) + bf2f((unsigned short)v1[k])) +
                               (bf2f((unsigned short)v2[k]) + bf2f((unsigned short)v3[k]))) +
                              ((bf2f((unsigned short)v4[k]) + bf2f((unsigned short)v5[k])) +
                               (bf2f((unsigned short)v6[k]) + bf2f((unsigned short)v7[k])));
            }
            for (; e + 2 <= end; e += 2) {
                int s0 = fetch(e), s1 = fetch(e + 1);
                short8 v0 = *(const short8*)(hp + (size_t)s0 * 64);
                short8 v1 = *(const short8*)(hp + (size_t)s1 * 64);
#pragma unroll
                for (int k = 0; k < 8; k++)
                    acc[k] += bf2f((unsigned short)v0[k]) + bf2f((unsigned short)v1[k]);
            }
            if (e < end) {
                int s = fetch(e);
                short8 v = *(const short8*)(hp + (size_t)s * 64);
#pragma unroll
                for (int k = 0; k < 8; k++) acc[k] += bf2f((unsigned short)v[k]);
            }
            short8 o;
#pragma unroll
            for (int k = 0; k < 8; k++) o[k] = (short)f2bf(acc[k] * sc);
            *(short8*)(atp + (c * 2 + (fs >> 2)) * 2048) = o;   // swizzled A-tile write
        }
    };
    if (ecount <= 2048)
        sweep([&](int e) { return eIdx[e]; });
    else
        sweep([&](int e) { return csr_src[ebeg + e]; });

    // ---- phase 2: GEMM. wave -> 32 rows x 64 cols.
    const int wr = (w >> 2) * 32;
    const int wc = (w & 3) * 64;
    floatx4 acc2[2][4];
#pragma unroll
    for (int i = 0; i < 2; i++)
#pragma unroll
        for (int j = 0; j < 4; j++) acc2[i][j] = (floatx4){0.f, 0.f, 0.f, 0.f};
    const int q = lane >> 4;
    const int ln = lane & 15;
    const int uf = (((ln & 1) << 2) | q) ^ ((ln >> 1) & 7);

    int buf = 0;
    for (int k0 = 0; k0 < K; k0 += 32) {
        __syncthreads();
        if (k0 + 32 < K) STAGEB(buf ^ 1, k0 + 32)
        const unsigned short* rA = At + (k0 >> 5) * 2048;
        const unsigned short* rB = Bs[buf];
        short8 af[2], bfr[4];
#pragma unroll
        for (int i = 0; i < 2; i++)
            af[i] = *(const short8*)(rA + (((wr + i * 16 + ln) >> 1) << 6) + uf * 8);
#pragma unroll
        for (int j = 0; j < 4; j++)
            bfr[j] = *(const short8*)(rB + (((wc + j * 16 + ln) >> 1) << 6) + uf * 8);
#pragma unroll
        for (int i = 0; i < 2; i++)
#pragma unroll
            for (int j = 0; j < 4; j++)
                acc2[i][j] = __builtin_amdgcn_mfma_f32_16x16x32_bf16(af[i], bfr[j], acc2[i][j], 0, 0, 0);
        buf ^= 1;
    }
#undef STAGEB

    // ---- phase 3: LN epilogue (+ *ns), chunk-major store
    float bcol[4];
#pragma unroll
    for (int j = 0; j < 4; j++) bcol[j] = bias[wc + j * 16 + ln];
    const int wcIdx = w & 3;
#pragma unroll
    for (int i = 0; i < 2; i++) {
#pragma unroll
        for (int rr = 0; rr < 4; rr++) {
            float s = 0.f, s2 = 0.f;
#pragma unroll
            for (int j = 0; j < 4; j++) {
                float v = acc2[i][j][rr] + bcol[j];
                v = v >= 0.f ? v : 0.01f * v;
                s += v; s2 += v * v;
            }
#pragma unroll
            for (int off = 8; off > 0; off >>= 1) {
                s += __shfl_down(s, off, 16);
                s2 += __shfl_down(s2, off, 16);
            }
            if (ln == 0) {
                int row = wr + i * 16 + q * 4 + rr;
                sSum[wcIdx][row] = s;
                sSum2[wcIdx][row] = s2;
            }
        }
    }
    __syncthreads();
    if (tid < 64) {
        float su = sSum[0][tid] + sSum[1][tid] + sSum[2][tid] + sSum[3][tid];
        float su2 = sSum2[0][tid] + sSum2[1][tid] + sSum2[2][tid] + sSum2[3][tid];
        float mu = su * (1.0f / 256.0f);
        float var = su2 * (1.0f / 256.0f) - mu * mu;
        float rs = rsqrtf(var + 1e-5f);
        float nsv = ns[n0 + tid];
        sMa[tid] = rs * nsv;
        sMb[tid] = -mu * rs * nsv;
    }
    __syncthreads();
#pragma unroll
    for (int i = 0; i < 2; i++) {
#pragma unroll
        for (int rr = 0; rr < 4; rr++) {
            int row = wr + i * 16 + q * 4 + rr;
            float a = sMa[row], bb = sMb[row];
#pragma unroll
            for (int j = 0; j < 4; j++) {
                float v = acc2[i][j][rr] + bcol[j];
                v = v >= 0.f ? v : 0.01f * v;
                int col = wc + j * 16 + ln;
                size_t off = (size_t)(col >> 6) * (N_NODES * 64) +
                             (size_t)(n0 + row) * 64 + (col & 63);
                ho[off] = f2bf(v * a + bb);
            }
        }
    }
}

// ------------------------------------------------ aggregation (layer 4 only)
__global__ __launch_bounds__(128, 8) void k_aggregate(
        const unsigned short* __restrict__ hs,   // chunk-major [4][N_NODES][64]
        const int* __restrict__ row_ptr,
        const int* __restrict__ csr_src,
        const float* __restrict__ nd,
        unsigned short* __restrict__ aggb) {     // row-major [N_NODES][256]
    __shared__ int eIdx[512];
    __shared__ int rp[17];
    const int tid = threadIdx.x;
    const int n0 = blockIdx.x * 16;
    if (tid <= 16) rp[tid] = row_ptr[n0 + tid];
    __syncthreads();
    const int ebeg = rp[0];
    const int ecount = rp[16] - ebeg;
    const int ecached = ecount < 512 ? ecount : 512;
    for (int i = tid; i < ecached; i += 128) eIdx[i] = csr_src[ebeg + i];
    __syncthreads();

    const int nl = tid >> 3;
    const int fs = tid & 7;
    const int n = n0 + nl;
    const int beg = rp[nl] - ebeg, end = rp[nl + 1] - ebeg;
    const float sc = nd[n];

    auto sweep = [&](auto fetch) {
        for (int c = 0; c < 4; c++) {
            const unsigned short* hp = hs + (size_t)c * (N_NODES * 64) + fs * 8;
            float acc[8];
#pragma unroll
            for (int k = 0; k < 8; k++) acc[k] = 0.f;
            int e = beg;
            for (; e + 8 <= end; e += 8) {
                int s0 = fetch(e),     s1 = fetch(e + 1), s2 = fetch(e + 2), s3 = fetch(e + 3);
                int s4 = fetch(e + 4), s5 = fetch(e + 5), s6 = fetch(e + 6), s7 = fetch(e + 7);
                short8 v0 = *(const short8*)(hp + (size_t)s0 * 64);
                short8 v1 = *(const short8*)(hp + (size_t)s1 * 64);
                short8 v2 = *(const short8*)(hp + (size_t)s2 * 64);
                short8 v3 = *(const short8*)(hp + (size_t)s3 * 64);
                short8 v4 = *(const short8*)(hp + (size_t)s4 * 64);
                short8 v5 = *(const short8*)(hp + (size_t)s5 * 64);
                short8 v6 = *(const short8*)(hp + (size_t)s6 * 64);
                short8 v7 = *(const short8*)(hp + (size_t)s7 * 64);
#pragma unroll
                for (int k = 0; k < 8; k++)
                    acc[k] += ((bf2f((unsigned short)v0[k]) + bf2f((unsigned short)v1[k])) +
                               (bf2f((unsigned short)v2[k]) + bf2f((unsigned short)v3[k]))) +
                              ((bf2f((unsigned short)v4[k]) + bf2f((unsigned short)v5[k])) +
                               (bf2f((unsigned short)v6[k]) + bf2f((unsigned short)v7[k])));
            }
            for (; e + 2 <= end; e += 2) {
                int s0 = fetch(e), s1 = fetch(e + 1);
                short8 v0 = *(const short8*)(hp + (size_t)s0 * 64);
                short8 v1 = *(const short8*)(hp + (size_t)s1 * 64);
#pragma unroll
                for (int k = 0; k < 8; k++)
                    acc[k] += bf2f((unsigned short)v0[k]) + bf2f((unsigned short)v1[k]);
            }
            if (e < end) {
                int s = fetch(e);
                short8 v = *(const short8*)(hp + (size_t)s * 64);
#pragma unroll
                for (int k = 0; k < 8; k++) acc[k] += bf2f((unsigned short)v[k]);
            }
            short8 o;
#pragma unroll
            for (int k = 0; k < 8; k++) o[k] = (short)f2bf(acc[k] * sc);
            __builtin_nontemporal_store(o, (short8*)(aggb + (size_t)n * 256 + c * 64 + fs * 8));
        }
    };
    if (ecount <= 512)
        sweep([&](int e) { return eIdx[e]; });
    else
        sweep([&](int e) { return csr_src[ebeg + e]; });
}

// ------------------------------------------------ bf16 MFMA GEMM (layer 4)
template <bool LEAKY, bool OUT_BF16>
__global__ __launch_bounds__(256) void gemm_mfma(
        const unsigned short* __restrict__ A, const unsigned short* __restrict__ Bt,
        const float* __restrict__ bias,
        void* __restrict__ Cv,
        int M, int N, int K) {
    __shared__ __align__(16) unsigned short As[2][128 * 32];
    __shared__ __align__(16) unsigned short Bs[2][128 * 32];
    const int tid = threadIdx.x;
    const int lane = tid & 63;
    const int w = tid >> 6;
    const int wr = (w >> 1) * 64;
    const int wc = (w & 1) * 64;
    const int rowBase = blockIdx.x * 128;
    const int colBase = blockIdx.y * 128;

    floatx4 acc[4][4];
#pragma unroll
    for (int i = 0; i < 4; i++)
#pragma unroll
        for (int j = 0; j < 4; j++) acc[i][j] = (floatx4){0.f, 0.f, 0.f, 0.f};

    const int pr = lane >> 3;
    const int uu = (lane & 7) ^ pr;
    const int srow = w * 32 + pr * 2 + (uu >> 2);
    const int kc = (uu & 3) * 8;
    const unsigned short* gA = A + (size_t)(rowBase + srow) * K + kc;
    const unsigned short* gB = Bt + (size_t)(colBase + srow) * K + kc;
    const int wbase = (w * 32) * 32;

    const int q = lane >> 4;
    const int ln = lane & 15;
    const int uf = (((ln & 1) << 2) | q) ^ ((ln >> 1) & 7);

    {
        unsigned short* lA = As[0] + wbase;
        unsigned short* lB = Bs[0] + wbase;
        __builtin_amdgcn_global_load_lds((const GLOBAL_AS short*)(gA),
                                         (LDS_AS short*)lA, 16, 0, 0);
        __builtin_amdgcn_global_load_lds((const GLOBAL_AS short*)(gA + (size_t)16 * K),
                                         (LDS_AS short*)(lA + 16 * 32), 16, 0, 0);
        __builtin_amdgcn_global_load_lds((const GLOBAL_AS short*)(gB),
                                         (LDS_AS short*)lB, 16, 0, 0);
        __builtin_amdgcn_global_load_lds((const GLOBAL_AS short*)(gB + (size_t)16 * K),
                                         (LDS_AS short*)(lB + 16 * 32), 16, 0, 0);
    }

    int buf = 0;
    for (int k0 = 0; k0 < K; k0 += 32) {
        __syncthreads();
        if (k0 + 32 < K) {
            unsigned short* lA = As[buf ^ 1] + wbase;
            unsigned short* lB = Bs[buf ^ 1] + wbase;
            __builtin_amdgcn_global_load_lds((const GLOBAL_AS short*)(gA + k0 + 32),
                                             (LDS_AS short*)lA, 16, 0, 0);
            __builtin_amdgcn_global_load_lds((const GLOBAL_AS short*)(gA + k0 + 32 + (size_t)16 * K),
                                             (LDS_AS short*)(lA + 16 * 32), 16, 0, 0);
            __builtin_amdgcn_global_load_lds((const GLOBAL_AS short*)(gB + k0 + 32),
                                             (LDS_AS short*)lB, 16, 0, 0);
            __builtin_amdgcn_global_load_lds((const GLOBAL_AS short*)(gB + k0 + 32 + (size_t)16 * K),
                                             (LDS_AS short*)(lB + 16 * 32), 16, 0, 0);
        }
        const unsigned short* rA = As[buf];
        const unsigned short* rB = Bs[buf];
        short8 af[4], bfr[4];
#pragma unroll
        for (int i = 0; i < 4; i++)
            af[i] = *(const short8*)(rA + (((wr + i * 16 + ln) >> 1) << 6) + uf * 8);
#pragma unroll
        for (int j = 0; j < 4; j++)
            bfr[j] = *(const short8*)(rB + (((wc + j * 16 + ln) >> 1) << 6) + uf * 8);
#pragma unroll
        for (int i = 0; i < 4; i++)
#pragma unroll
            for (int j = 0; j < 4; j++)
                acc[i][j] = __builtin_amdgcn_mfma_f32_16x16x32_bf16(af[i], bfr[j], acc[i][j], 0, 0, 0);
        buf ^= 1;
    }
#pragma unroll
    for (int i = 0; i < 4; i++) {
#pragma unroll
        for (int j = 0; j < 4; j++) {
#pragma unroll
            for (int r = 0; r < 4; r++) {
                int row = rowBase + wr + i * 16 + q * 4 + r;
                int col = colBase + wc + j * 16 + ln;
                float v = acc[i][j][r] + bias[col];
                if (LEAKY) v = v >= 0.f ? v : 0.01f * v;
                if (OUT_BF16)
                    ((unsigned short*)Cv)[(size_t)row * N + col] = f2bf(v);
                else
                    ((float*)Cv)[(size_t)row * N + col] = v;
            }
        }
    }
}

// ------------------------------------------------ heads GEMM, K-split x8 -> fp32 partials
__global__ __launch_bounds__(256) void gemm_heads(
        const unsigned short* __restrict__ A,   // pooledb [128][1024] bf16
        const unsigned short* __restrict__ Bt,  // [Wmt;Wst] [2048][1024] bf16
        float* __restrict__ P) {                // [8][128][2048] fp32
    __shared__ __align__(16) unsigned short As[2][128 * 32];
    __shared__ __align__(16) unsigned short Bs[2][128 * 32];
    const int tid = threadIdx.x;
    const int lane = tid & 63;
    const int w = tid >> 6;
    const int wr = (w >> 1) * 64;
    const int wc = (w & 1) * 64;
    const int colBase = blockIdx.x * 128;
    const int ks = blockIdx.y;
    const int K = 1024;

    floatx4 acc[4][4];
#pragma unroll
    for (int i = 0; i < 4; i++)
#pragma unroll
        for (int j = 0; j < 4; j++) acc[i][j] = (floatx4){0.f, 0.f, 0.f, 0.f};

    const int pr = lane >> 3;
    const int uu = (lane & 7) ^ pr;
    const int srow = w * 32 + pr * 2 + (uu >> 2);
    const int kc = (uu & 3) * 8;
    const unsigned short* gA = A + (size_t)srow * K + ks * 128 + kc;
    const unsigned short* gB = Bt + (size_t)(colBase + srow) * K + ks * 128 + kc;
    const int wbase = (w * 32) * 32;

    const int q = lane >> 4;
    const int ln = lane & 15;
    const int uf = (((ln & 1) << 2) | q) ^ ((ln >> 1) & 7);

    {
        unsigned short* lA = As[0] + wbase;
        unsigned short* lB = Bs[0] + wbase;
        __builtin_amdgcn_global_load_lds((const GLOBAL_AS short*)(gA),
                                         (LDS_AS short*)lA, 16, 0, 0);
        __builtin_amdgcn_global_load_lds((const GLOBAL_AS short*)(gA + (size_t)16 * K),
                                         (LDS_AS short*)(lA + 16 * 32), 16, 0, 0);
        __builtin_amdgcn_global_load_lds((const GLOBAL_AS short*)(gB),
                                         (LDS_AS short*)lB, 16, 0, 0);
        __builtin_amdgcn_global_load_lds((const GLOBAL_AS short*)(gB + (size_t)16 * K),
                                         (LDS_AS short*)(lB + 16 * 32), 16, 0, 0);
    }

    int buf = 0;
    for (int k0 = 0; k0 < 128; k0 += 32) {
        __syncthreads();
        if (k0 + 32 < 128) {
            unsigned short* lA = As[buf ^ 1] + wbase;
            unsigned short* lB = Bs[buf ^ 1] + wbase;
            __builtin_amdgcn_global_load_lds((const GLOBAL_AS short*)(gA + k0 + 32),
                                             (LDS_AS short*)lA, 16, 0, 0);
            __builtin_amdgcn_global_load_lds((const GLOBAL_AS short*)(gA + k0 + 32 + (size_t)16 * K),
                                             (LDS_AS short*)(lA + 16 * 32), 16, 0, 0);
            __builtin_amdgcn_global_load_lds((const GLOBAL_AS short*)(gB + k0 + 32),
                                             (LDS_AS short*)lB, 16, 0, 0);
            __builtin_amdgcn_global_load_lds((const GLOBAL_AS short*)(gB + k0 + 32 + (size_t)16 * K),
                                             (LDS_AS short*)(lB + 16 * 32), 16, 0, 0);
        }
        const unsigned short* rA = As[buf];
        const unsigned short* rB = Bs[buf];
        short8 af[4], bfr[4];
#pragma unroll
        for (int i = 0; i < 4; i++)
            af[i] = *(const short8*)(rA + (((wr + i * 16 + ln) >> 1) << 6) + uf * 8);
#pragma unroll
        for (int j = 0; j < 4; j++)
            bfr[j] = *(const short8*)(rB + (((wc + j * 16 + ln) >> 1) << 6) + uf * 8);
#pragma unroll
        for (int i = 0; i < 4; i++)
#pragma unroll
            for (int j = 0; j < 4; j++)
                acc[i][j] = __builtin_amdgcn_mfma_f32_16x16x32_bf16(af[i], bfr[j], acc[i][j], 0, 0, 0);
        buf ^= 1;
    }
    float* Pk = P + (size_t)ks * 128 * 2048;
#pragma unroll
    for (int i = 0; i < 4; i++) {
#pragma unroll
        for (int j = 0; j < 4; j++) {
#pragma unroll
            for (int r = 0; r < 4; r++) {
                int row = wr + i * 16 + q * 4 + r;
                int col = colBase + wc + j * 16 + ln;
                Pk[(size_t)row * 2048 + col] = acc[i][j][r];
            }
        }
    }
}

__global__ __launch_bounds__(256) void k_heads_reduce(
        const float* __restrict__ P, const float* __restrict__ bm,
        const float* __restrict__ bsd, float* __restrict__ out) {
    int idx = blockIdx.x * 256 + threadIdx.x;
    int row = idx >> 9;
    int col = (idx & 511) * 4;
    floatx4 s = (floatx4){0.f, 0.f, 0.f, 0.f};
#pragma unroll
    for (int p = 0; p < 8; p++)
        s += *(const floatx4*)(P + (size_t)p * 128 * 2048 + (size_t)row * 2048 + col);
    bool hi = col >= 1024;
    const float* bias = hi ? bsd : bm;
    int bc = hi ? col - 1024 : col;
    s += *(const floatx4*)(bias + bc);
    float* o = hi ? (out + (size_t)128 * 1024 + (size_t)row * 1024 + bc)
                  : (out + (size_t)row * 1024 + col);
    *(floatx4*)o = s;
}

// ------------------------------------------------ fused per-node LN(1024) + partial mean-pool
__global__ __launch_bounds__(256) void k_lnpool(const unsigned short* __restrict__ h4,
                                                float* __restrict__ partial) {
    const int g = blockIdx.y, p = blockIdx.x;
    const int w = threadIdx.x >> 6, lane = threadIdx.x & 63;
    float acc[16];
#pragma unroll
    for (int k = 0; k < 16; k++) acc[k] = 0.f;
    for (int i = 0; i < 8; i++) {
        int node = (g * 8 + p) * 32 + w * 8 + i;
        const unsigned short* row = h4 + (size_t)node * 1024 + lane * 16;
        short8 a = *(const short8*)row;
        short8 b = *(const short8*)(row + 8);
        float v[16];
#pragma unroll
        for (int k = 0; k < 8; k++) v[k] = bf2f((unsigned short)a[k]);
#pragma unroll
        for (int k = 0; k < 8; k++) v[8 + k] = bf2f((unsigned short)b[k]);
        float s = 0.f, s2 = 0.f;
#pragma unroll
        for (int k = 0; k < 16; k++) { s += v[k]; s2 += v[k] * v[k]; }
#pragma unroll
        for (int off = 32; off > 0; off >>= 1) {
            s += __shfl_down(s, off);
            s2 += __shfl_down(s2, off);
        }
        s = __shfl(s, 0);
        s2 = __shfl(s2, 0);
        float mu = s * (1.0f / 1024.0f);
        float var = s2 * (1.0f / 1024.0f) - mu * mu;
        float rs = rsqrtf(var + 1e-5f);
#pragma unroll
        for (int k = 0; k < 16; k++) acc[k] += (v[k] - mu) * rs;
    }
    __shared__ float red[4][1024];
    float* my = red[w] + lane * 16;
#pragma unroll
    for (int k = 0; k < 16; k++) my[k] = acc[k];
    __syncthreads();
    int t = threadIdx.x;
    floatx4 o = (floatx4){0.f, 0.f, 0.f, 0.f};
#pragma unroll
    for (int w2 = 0; w2 < 4; w2++) {
        const floatx4 v = *(const floatx4*)(red[w2] + t * 4);
        o += v;
    }
    __builtin_nontemporal_store(o, (floatx4*)(partial + (size_t)(g * 8 + p) * 1024 + t * 4));
}

__global__ __launch_bounds__(256) void k_pool_final(const float* __restrict__ partial,
                                                    unsigned short* __restrict__ pooledb) {
    int g = blockIdx.x, t = threadIdx.x;
    int wave = t >> 6;
    float4 a = make_float4(0.f, 0.f, 0.f, 0.f);
    for (int p = 0; p < 8; p++) {
        float4 v = *(const float4*)(partial + (size_t)(g * 8 + p) * 1024 + t * 4);
        a.x += v.x; a.y += v.y; a.z += v.z; a.w += v.w;
    }
    const float invn = 1.0f / 256.0f;
    a.x *= invn; a.y *= invn; a.z *= invn; a.w *= invn;
    float s = a.x + a.y + a.z + a.w;
    float s2 = a.x * a.x + a.y * a.y + a.z * a.z + a.w * a.w;
#pragma unroll
    for (int off = 32; off > 0; off >>= 1) {
        s += __shfl_down(s, off);
        s2 += __shfl_down(s2, off);
    }
    __shared__ float ss[4], ss2[4];
    if ((t & 63) == 0) { ss[wave] = s; ss2[wave] = s2; }
    __syncthreads();
    if (t == 0) {
        float tt = 0.f, tt2 = 0.f;
        for (int w = 0; w < 4; w++) { tt += ss[w]; tt2 += ss2[w]; }
        float mu = tt / 1024.f;
        float var = tt2 / 1024.f - mu * mu;
        ss[0] = mu;
        ss2[0] = rsqrtf(var + 1e-5f);
    }
    __syncthreads();
    float mu = ss[0], inv = ss2[0];
    ushort4 o;
    o.x = f2bf((a.x - mu) * inv); o.y = f2bf((a.y - mu) * inv);
    o.z = f2bf((a.z - mu) * inv); o.w = f2bf((a.w - mu) * inv);
    *(ushort4*)(pooledb + (size_t)g * 1024 + t * 4) = o;
}

// ---------------------------------------------------------------- launch
extern "C" void kernel_launch(void* const* d_in, const int* in_sizes, int n_in,
                              void* d_out, int out_size, void* d_ws, size_t ws_size,
                              hipStream_t stream) {
    const float* x  = (const float*)d_in[0];
    const int*   src = (const int*)d_in[1];
    const int*   dst = (const int*)d_in[2];
    const float* W1 = (const float*)d_in[3];  const float* b1 = (const float*)d_in[4];
    const float* W2 = (const float*)d_in[5];  const float* b2 = (const float*)d_in[6];
    const float* W3 = (const float*)d_in[7];  const float* b3 = (const float*)d_in[8];
    const float* W4 = (const float*)d_in[9];  const float* b4 = (const float*)d_in[10];
    const float* Wm = (const float*)d_in[11]; const float* bm = (const float*)d_in[12];
    const float* Wsd = (const float*)d_in[13]; const float* bsd = (const float*)d_in[14];
    float* out = (float*)d_out;

    char* w = (char*)d_ws;
    unsigned short* aggb = (unsigned short*)w; w += (size_t)N_NODES * 256 * 2;
    unsigned short* hsbA = (unsigned short*)w; w += (size_t)N_NODES * 256 * 2;
    unsigned short* hsbB = (unsigned short*)w; w += (size_t)N_NODES * 256 * 2;
    unsigned short* h4b  = (unsigned short*)w; w += (size_t)N_NODES * 1024 * 2;
    float* partial = (float*)w; w += (size_t)128 * 8 * 1024 * 4;
    unsigned short* pooledb = (unsigned short*)w; w += (size_t)128 * 1024 * 2;
    unsigned short* W1t = (unsigned short*)w; w += (size_t)256 * 256 * 2;
    unsigned short* W2t = (unsigned short*)w; w += (size_t)256 * 256 * 2;
    unsigned short* W3t = (unsigned short*)w; w += (size_t)256 * 256 * 2;
    unsigned short* W4t = (unsigned short*)w; w += (size_t)256 * 1024 * 2;
    unsigned short* Wmt = (unsigned short*)w; w += (size_t)1024 * 1024 * 2;  // Wst must follow
    unsigned short* Wst = (unsigned short*)w; w += (size_t)1024 * 1024 * 2;  // contiguous: cat
    float* ns     = (float*)w; w += (size_t)N_NODES * 4;
    float* nd     = (float*)w; w += (size_t)N_NODES * 4;
    unsigned int* histOut32 = (unsigned int*)w; w += (size_t)128 * 8192 * 4;
    unsigned int* histIn32  = (unsigned int*)w; w += (size_t)128 * 8192 * 4;
    unsigned int* pre32     = (unsigned int*)w; w += (size_t)128 * 8192 * 4;
    int* in_deg   = (int*)w;   w += (size_t)N_NODES * 4;
    int* row_ptr  = (int*)w;   w += (size_t)(N_NODES + 1) * 4;
    int* csr_src  = (int*)w;   w += (size_t)N_EDGES * 4;
    // heads partials reuse hist area (dead after k_place): 8 MB needed
    float* headp = (float*)histOut32;

    // weights (independent of graph work)
    TransDescs td;
    td.W[0] = W1; td.W[1] = W2; td.W[2] = W3; td.W[3] = W4; td.W[4] = Wm; td.W[5] = Wsd;
    td.Wt[0] = W1t; td.Wt[1] = W2t; td.Wt[2] = W3t; td.Wt[3] = W4t; td.Wt[4] = Wmt; td.Wt[5] = Wst;
    td.K[0] = 256; td.K[1] = 256; td.K[2] = 256; td.K[3] = 256; td.K[4] = 1024; td.K[5] = 1024;
    td.N[0] = 256; td.N[1] = 256; td.N[2] = 256; td.N[3] = 1024; td.N[4] = 1024; td.N[5] = 1024;
    td.end[0] = 64; td.end[1] = 128; td.end[2] = 192; td.end[3] = 448; td.end[4] = 1472; td.end[5] = 2496;
    k_transpose_all<<<2496, 256, 0, stream>>>(td);

    // atomic-free graph preprocessing
    k_hist<<<128, 256, 0, stream>>>(src, dst, histOut32, histIn32);
    k_merge<<<32, 256, 0, stream>>>(histOut32, histIn32, pre32, in_deg, ns, nd);
    k_scan<<<1, 1024, 0, stream>>>(in_deg, row_ptr);
    k_place<<<128, 256, 0, stream>>>(src, dst, pre32, row_ptr, csr_src);

    // layer-1 gather table: x * ns -> bf16 (chunk-major slabs)
    k_scale_x<<<N_NODES * 256 / 1024, 256, 0, stream>>>(x, ns, hsbA);

    // layers 1-3: fully fused gather+GEMM+LN, ping-pong tables
    const unsigned short* Wts[3] = {W1t, W2t, W3t};
    const float* bs3[3] = {b1, b2, b3};
    unsigned short* tin = hsbA;
    unsigned short* tout = hsbB;
    for (int l = 0; l < 3; l++) {
        fused_layer<<<N_NODES / 64, 512, 0, stream>>>(tin, row_ptr, csr_src, nd,
                                                      Wts[l], bs3[l], ns, tout);
        unsigned short* tmp = tin; tin = tout; tout = tmp;
    }
    // tin now holds layer-3 output

    // layer 4 (256 -> 1024), bf16 out; LN fused into pool
    k_aggregate<<<N_NODES / 16, 128, 0, stream>>>(tin, row_ptr, csr_src, nd, aggb);
    gemm_mfma<true, true><<<dim3(N_NODES / 128, 8), 256, 0, stream>>>(
        aggb, W4t, b4, h4b, N_NODES, 1024, 256);

    // per-node LN + mean pool + final LN -> bf16
    k_lnpool<<<dim3(8, 128), 256, 0, stream>>>(h4b, partial);
    k_pool_final<<<128, 256, 0, stream>>>(partial, pooledb);

    // heads: K-split x8 GEMM (128 blocks) -> fp32 partials -> reduce+bias+split
    gemm_heads<<<dim3(16, 8), 256, 0, stream>>>(pooledb, Wmt, headp);
    k_heads_reduce<<<256, 256, 0, stream>>>(headp, bm, bsd, out);
}

// Round 8
// 334.736 us; speedup vs baseline: 1.2790x; 1.0859x over previous
//
#include <hip/hip_runtime.h>

#define N_NODES 32768
#define N_EDGES 524288

typedef __attribute__((ext_vector_type(8))) short short8;
typedef __attribute__((ext_vector_type(4))) float floatx4;

#define GLOBAL_AS __attribute__((address_space(1)))
#define LDS_AS __attribute__((address_space(3)))

__device__ __forceinline__ unsigned short f2bf(float x) {
    union { float f; unsigned u; } v; v.f = x;
    unsigned r = v.u + 0x7FFF + ((v.u >> 16) & 1);
    return (unsigned short)(r >> 16);
}
__device__ __forceinline__ float bf2f(unsigned short u) {
    union { unsigned u; float f; } v; v.u = ((unsigned)u) << 16;
    return v.f;
}

// ================================================================ graph preprocessing
// Atomic-free CSR build. Round 8: k_merge widened 32->256 blocks (2-pass packed
// partial sums), k_scan widened 1->32 blocks (2-pass). Bitwise-identical outputs.

__global__ __launch_bounds__(256) void k_hist(const int* __restrict__ src,
                                              const int* __restrict__ dst,
                                              unsigned int* __restrict__ histOut32,
                                              unsigned int* __restrict__ histIn32) {
    __shared__ unsigned int hOut[8192];
    __shared__ unsigned int hIn[8192];
    int t = threadIdx.x, b = blockIdx.x;
    for (int i = t; i < 8192; i += 256) { hOut[i] = 0; hIn[i] = 0; }
    __syncthreads();
    int base = b * 4096;
    for (int i = t; i < 4096; i += 256) {
        int s = src[base + i], d = dst[base + i];
        atomicAdd(&hOut[s >> 2], 1u << ((s & 3) * 8));
        atomicAdd(&hIn[d >> 2], 1u << ((d & 3) * 8));
    }
    __syncthreads();
    for (int i = t; i < 8192; i += 256) {
        histOut32[b * 8192 + i] = hOut[i];
        histIn32[b * 8192 + i] = hIn[i];
    }
}

// pass 1: per-(16-block group) packed sums. grid (32, 8) x 256 thr.
__global__ __launch_bounds__(256) void k_merge_p1(const unsigned int* __restrict__ histIn32,
                                                  const unsigned int* __restrict__ histOut32,
                                                  unsigned int* __restrict__ partIn,
                                                  unsigned int* __restrict__ partOut) {
    int g = blockIdx.x * 256 + threadIdx.x;
    int bg = blockIdx.y;
    unsigned int si = 0, so = 0;
#pragma unroll
    for (int j = 0; j < 16; j++) {
        si += histIn32[(bg * 16 + j) * 8192 + g];
        so += histOut32[(bg * 16 + j) * 8192 + g];
    }
    partIn[bg * 8192 + g] = si;
    partOut[bg * 8192 + g] = so;
}

// pass 2: exact packed pre32 prefixes + in_deg/ns/nd. grid (32, 8) x 256 thr.
__global__ __launch_bounds__(256) void k_merge_p2(const unsigned int* __restrict__ histIn32,
                                                  const unsigned int* __restrict__ partIn,
                                                  const unsigned int* __restrict__ partOut,
                                                  unsigned int* __restrict__ pre32,
                                                  int* __restrict__ in_deg,
                                                  float* __restrict__ ns,
                                                  float* __restrict__ nd) {
    int g = blockIdx.x * 256 + threadIdx.x;
    int bg = blockIdx.y;
    unsigned int run = 0;
    for (int b2 = 0; b2 < bg; b2++) run += partIn[b2 * 8192 + g];
    for (int j = 0; j < 16; j++) {
        int b = bg * 16 + j;
        pre32[b * 8192 + g] = run;
        run += histIn32[b * 8192 + g];
    }
    if (bg == 7) {  // run == packed total in-degree
        int r0 = run & 255, r1 = (run >> 8) & 255, r2 = (run >> 16) & 255, r3 = (run >> 24) & 255;
        in_deg[g * 4 + 0] = r0; in_deg[g * 4 + 1] = r1;
        in_deg[g * 4 + 2] = r2; in_deg[g * 4 + 3] = r3;
        nd[g * 4 + 0] = r0 > 0 ? rsqrtf((float)r0) : 1.0f;
        nd[g * 4 + 1] = r1 > 0 ? rsqrtf((float)r1) : 1.0f;
        nd[g * 4 + 2] = r2 > 0 ? rsqrtf((float)r2) : 1.0f;
        nd[g * 4 + 3] = r3 > 0 ? rsqrtf((float)r3) : 1.0f;
    }
    if (bg == 0) {
        unsigned int to = 0;
#pragma unroll
        for (int b2 = 0; b2 < 8; b2++) to += partOut[b2 * 8192 + g];
        int r0 = to & 255, r1 = (to >> 8) & 255, r2 = (to >> 16) & 255, r3 = (to >> 24) & 255;
        ns[g * 4 + 0] = r0 > 0 ? rsqrtf((float)r0) : 1.0f;
        ns[g * 4 + 1] = r1 > 0 ? rsqrtf((float)r1) : 1.0f;
        ns[g * 4 + 2] = r2 > 0 ? rsqrtf((float)r2) : 1.0f;
        ns[g * 4 + 3] = r3 > 0 ? rsqrtf((float)r3) : 1.0f;
    }
}

// scan pass A: block-local prefix (32 blocks x 256 thr x 4 nodes).
__global__ __launch_bounds__(256) void k_scanA(const int* __restrict__ in_deg,
                                               int* __restrict__ row_ptr,
                                               int* __restrict__ blkSum) {
    __shared__ int part[256];
    int t = threadIdx.x, b = blockIdx.x;
    int base = (b * 256 + t) * 4;
    int l0 = in_deg[base], l1 = in_deg[base + 1], l2 = in_deg[base + 2], l3 = in_deg[base + 3];
    part[t] = l0 + l1 + l2 + l3;
    __syncthreads();
    for (int off = 1; off < 256; off <<= 1) {
        int v = (t >= off) ? part[t - off] : 0;
        __syncthreads();
        part[t] += v;
        __syncthreads();
    }
    int excl = (t == 0) ? 0 : part[t - 1];
    row_ptr[base] = excl;
    row_ptr[base + 1] = excl + l0;
    row_ptr[base + 2] = excl + l0 + l1;
    row_ptr[base + 3] = excl + l0 + l1 + l2;
    if (t == 255) blkSum[b] = part[255];
}

// scan pass C: add block offsets.
__global__ __launch_bounds__(256) void k_scanC(const int* __restrict__ blkSum,
                                               int* __restrict__ row_ptr) {
    __shared__ int soff;
    int t = threadIdx.x, b = blockIdx.x;
    if (t == 0) {
        int s = 0;
        for (int i = 0; i < b; i++) s += blkSum[i];
        soff = s;
    }
    __syncthreads();
    int base = (b * 256 + t) * 4;
    row_ptr[base] += soff; row_ptr[base + 1] += soff;
    row_ptr[base + 2] += soff; row_ptr[base + 3] += soff;
    if (b == 31 && t == 255) row_ptr[N_NODES] = soff + blkSum[31];
}

__global__ __launch_bounds__(256) void k_place(const int* __restrict__ src,
                                               const int* __restrict__ dst,
                                               const unsigned int* __restrict__ pre32,
                                               const int* __restrict__ row_ptr,
                                               int* __restrict__ csr_src) {
    __shared__ unsigned int cur[8192];
    int t = threadIdx.x, b = blockIdx.x;
    for (int i = t; i < 8192; i += 256) cur[i] = 0;
    __syncthreads();
    int base = b * 4096;
    const unsigned int* preb = pre32 + b * 8192;
    for (int i = t; i < 4096; i += 256) {
        int s = src[base + i], d = dst[base + i];
        int sh = (d & 3) * 8;
        unsigned int old = atomicAdd(&cur[d >> 2], 1u << sh);
        int rank = (old >> sh) & 255;
        int pb = (preb[d >> 2] >> sh) & 255;
        csr_src[row_ptr[d] + pb + rank] = s;
    }
}

// ---------------------------------------------- all 6 weight transposes in ONE kernel
struct TransDescs {
    const float* W[6];
    unsigned short* Wt[6];
    int K[6], N[6];
    int end[6];
};

__global__ __launch_bounds__(256) void k_transpose_all(TransDescs d) {
    int id = blockIdx.x, s = 0;
#pragma unroll
    for (int i = 0; i < 6; i++) if (id >= d.end[i]) s = i + 1;
    int base = (s == 0) ? 0 : d.end[s - 1];
    int t = id - base;
    int K = d.K[s], N = d.N[s];
    int ncols = N >> 5;
    int n0 = (t % ncols) * 32, k0 = (t / ncols) * 32;
    const float* W = d.W[s];
    unsigned short* Wt = d.Wt[s];
    __shared__ float tile[32][33];
    int tx = threadIdx.x & 31, ty = threadIdx.x >> 5;
    for (int r = 0; r < 32; r += 8)
        tile[ty + r][tx] = W[(size_t)(k0 + ty + r) * N + n0 + tx];
    __syncthreads();
    for (int r = 0; r < 32; r += 8)
        Wt[(size_t)(n0 + ty + r) * K + k0 + tx] = f2bf(tile[tx][ty + r]);
}

// ---------------------------------------------- x * ns[node] -> CHUNK-MAJOR bf16 table
__global__ __launch_bounds__(256) void k_scale_x(const float* __restrict__ x,
                                                 const float* __restrict__ ns,
                                                 unsigned short* __restrict__ xsb) {
    int i = blockIdx.x * 256 + threadIdx.x;  // float4 index
    float4 v = ((const float4*)x)[i];
    int n = i >> 6;
    int f = (i & 63) * 4;
    float sc = ns[n];
    ushort4 o;
    o.x = f2bf(v.x * sc); o.y = f2bf(v.y * sc);
    o.z = f2bf(v.z * sc); o.w = f2bf(v.w * sc);
    size_t off = (size_t)(f >> 6) * (N_NODES * 64) + (size_t)n * 64 + (f & 63);
    *(ushort4*)(xsb + off) = o;
}

// ================================================================ FUSED layer (1-3)
// Block = 64 output nodes, 512 threads, 2 blocks/CU. Gather A-tile into swizzled
// LDS -> K-loop MFMA (B via global_load_lds dbuf) -> LN epilogue -> chunk-major out.
__global__ __launch_bounds__(512, 4) void fused_layer(
        const unsigned short* __restrict__ hs,
        const int* __restrict__ row_ptr,
        const int* __restrict__ csr_src,
        const float* __restrict__ nd,
        const unsigned short* __restrict__ Bt,   // [256][256]
        const float* __restrict__ bias,
        const float* __restrict__ ns,
        unsigned short* __restrict__ ho) {
    __shared__ __align__(16) unsigned short At[8 * 2048];
    __shared__ __align__(16) unsigned short Bs[2][256 * 32];
    __shared__ int eIdx[2048];
    __shared__ int rp[65];
    __shared__ float sSum[4][64], sSum2[4][64], sMa[64], sMb[64];
    const int tid = threadIdx.x;
    const int lane = tid & 63;
    const int w = tid >> 6;
    const int n0 = blockIdx.x * 64;
    const int K = 256;

    const int pr = lane >> 3;
    const int uu = (lane & 7) ^ pr;
    const int rowInGrp = pr * 2 + (uu >> 2);
    const int kc = (uu & 3) * 8;
    const unsigned short* gB = Bt + (size_t)(w * 32 + rowInGrp) * K + kc;
    const int bBase = (w * 32) * 32;
#define STAGEB(buf_, koff_)                                                              \
    {                                                                                    \
        unsigned short* lB = Bs[buf_] + bBase;                                           \
        __builtin_amdgcn_global_load_lds((const GLOBAL_AS short*)(gB + (koff_)),         \
                                         (LDS_AS short*)lB, 16, 0, 0);                   \
        __builtin_amdgcn_global_load_lds((const GLOBAL_AS short*)(gB + (koff_) + (size_t)16 * K), \
                                         (LDS_AS short*)(lB + 16 * 32), 16, 0, 0);       \
    }
    STAGEB(0, 0)

    if (tid <= 64) rp[tid] = row_ptr[n0 + tid];
    __syncthreads();
    const int ebeg = rp[0];
    const int ecount = rp[64] - ebeg;
    const int ecached = ecount < 2048 ? ecount : 2048;
    for (int i = tid; i < ecached; i += 512) eIdx[i] = csr_src[ebeg + i];
    __syncthreads();

    const int r = tid >> 3;
    const int fs = tid & 7;
    const int beg = rp[r] - ebeg, end = rp[r + 1] - ebeg;
    const float sc = nd[n0 + r];
    const int rowpair = r >> 1;
    unsigned short* atp = At + rowpair * 64 +
                          (((((r & 1) << 2) | (fs & 3)) ^ (rowpair & 7)) << 3);

    auto sweep = [&](auto fetch) {
        for (int c = 0; c < 4; c++) {
            const unsigned short* hp = hs + (size_t)c * (N_NODES * 64) + fs * 8;
            float acc[8];
#pragma unroll
            for (int k = 0; k < 8; k++) acc[k] = 0.f;
            int e = beg;
            for (; e + 8 <= end; e += 8) {
                int s0 = fetch(e),     s1 = fetch(e + 1), s2 = fetch(e + 2), s3 = fetch(e + 3);
                int s4 = fetch(e + 4), s5 = fetch(e + 5), s6 = fetch(e + 6), s7 = fetch(e + 7);
                short8 v0 = *(const short8*)(hp + (size_t)s0 * 64);
                short8 v1 = *(const short8*)(hp + (size_t)s1 * 64);
                short8 v2 = *(const short8*)(hp + (size_t)s2 * 64);
                short8 v3 = *(const short8*)(hp + (size_t)s3 * 64);
                short8 v4 = *(const short8*)(hp + (size_t)s4 * 64);
                short8 v5 = *(const short8*)(hp + (size_t)s5 * 64);
                short8 v6 = *(const short8*)(hp + (size_t)s6 * 64);
                short8 v7 = *(const short8*)(hp + (size_t)s7 * 64);
#pragma unroll
                for (int k = 0; k < 8; k++)
                    acc[k] += ((bf2f((unsigned short)v0[k]) + bf2f((unsigned short)v1[k])) +
                               (bf2f((unsigned short)v2[k]) + bf2f((unsigned short)v3[k]))) +
                              ((bf2f((unsigned short)v4[k]) + bf2f((unsigned short)v5[k])) +
                               (bf2f((unsigned short)v6[k]) + bf2f((unsigned short)v7[k])));
            }
            for (; e + 2 <= end; e += 2) {
                int s0 = fetch(e), s1 = fetch(e + 1);
                short8 v0 = *(const short8*)(hp + (size_t)s0 * 64);
                short8 v1 = *(const short8*)(hp + (size_t)s1 * 64);
#pragma unroll
                for (int k = 0; k < 8; k++)
                    acc[k] += bf2f((unsigned short)v0[k]) + bf2f((unsigned short)v1[k]);
            }
            if (e < end) {
                int s = fetch(e);
                short8 v = *(const short8*)(hp + (size_t)s * 64);
#pragma unroll
                for (int k = 0; k < 8; k++) acc[k] += bf2f((unsigned short)v[k]);
            }
            short8 o;
#pragma unroll
            for (int k = 0; k < 8; k++) o[k] = (short)f2bf(acc[k] * sc);
            *(short8*)(atp + (c * 2 + (fs >> 2)) * 2048) = o;
        }
    };
    if (ecount <= 2048)
        sweep([&](int e) { return eIdx[e]; });
    else
        sweep([&](int e) { return csr_src[ebeg + e]; });

    const int wr = (w >> 2) * 32;
    const int wc = (w & 3) * 64;
    floatx4 acc2[2][4];
#pragma unroll
    for (int i = 0; i < 2; i++)
#pragma unroll
        for (int j = 0; j < 4; j++) acc2[i][j] = (floatx4){0.f, 0.f, 0.f, 0.f};
    const int q = lane >> 4;
    const int ln = lane & 15;
    const int uf = (((ln & 1) << 2) | q) ^ ((ln >> 1) & 7);

    int buf = 0;
    for (int k0 = 0; k0 < K; k0 += 32) {
        __syncthreads();
        if (k0 + 32 < K) STAGEB(buf ^ 1, k0 + 32)
        const unsigned short* rA = At + (k0 >> 5) * 2048;
        const unsigned short* rB = Bs[buf];
        short8 af[2], bfr[4];
#pragma unroll
        for (int i = 0; i < 2; i++)
            af[i] = *(const short8*)(rA + (((wr + i * 16 + ln) >> 1) << 6) + uf * 8);
#pragma unroll
        for (int j = 0; j < 4; j++)
            bfr[j] = *(const short8*)(rB + (((wc + j * 16 + ln) >> 1) << 6) + uf * 8);
#pragma unroll
        for (int i = 0; i < 2; i++)
#pragma unroll
            for (int j = 0; j < 4; j++)
                acc2[i][j] = __builtin_amdgcn_mfma_f32_16x16x32_bf16(af[i], bfr[j], acc2[i][j], 0, 0, 0);
        buf ^= 1;
    }
#undef STAGEB

    float bcol[4];
#pragma unroll
    for (int j = 0; j < 4; j++) bcol[j] = bias[wc + j * 16 + ln];
    const int wcIdx = w & 3;
#pragma unroll
    for (int i = 0; i < 2; i++) {
#pragma unroll
        for (int rr = 0; rr < 4; rr++) {
            float s = 0.f, s2 = 0.f;
#pragma unroll
            for (int j = 0; j < 4; j++) {
                float v = acc2[i][j][rr] + bcol[j];
                v = v >= 0.f ? v : 0.01f * v;
                s += v; s2 += v * v;
            }
#pragma unroll
            for (int off = 8; off > 0; off >>= 1) {
                s += __shfl_down(s, off, 16);
                s2 += __shfl_down(s2, off, 16);
            }
            if (ln == 0) {
                int row = wr + i * 16 + q * 4 + rr;
                sSum[wcIdx][row] = s;
                sSum2[wcIdx][row] = s2;
            }
        }
    }
    __syncthreads();
    if (tid < 64) {
        float su = sSum[0][tid] + sSum[1][tid] + sSum[2][tid] + sSum[3][tid];
        float su2 = sSum2[0][tid] + sSum2[1][tid] + sSum2[2][tid] + sSum2[3][tid];
        float mu = su * (1.0f / 256.0f);
        float var = su2 * (1.0f / 256.0f) - mu * mu;
        float rs = rsqrtf(var + 1e-5f);
        float nsv = ns[n0 + tid];
        sMa[tid] = rs * nsv;
        sMb[tid] = -mu * rs * nsv;
    }
    __syncthreads();
#pragma unroll
    for (int i = 0; i < 2; i++) {
#pragma unroll
        for (int rr = 0; rr < 4; rr++) {
            int row = wr + i * 16 + q * 4 + rr;
            float a = sMa[row], bb = sMb[row];
#pragma unroll
            for (int j = 0; j < 4; j++) {
                float v = acc2[i][j][rr] + bcol[j];
                v = v >= 0.f ? v : 0.01f * v;
                int col = wc + j * 16 + ln;
                size_t off = (size_t)(col >> 6) * (N_NODES * 64) +
                             (size_t)(n0 + row) * 64 + (col & 63);
                ho[off] = f2bf(v * a + bb);
            }
        }
    }
}

// ================================================================ FUSED layer 4
// Same gather-into-LDS A-tile, then 4 column-tiles of W4 (256 cols each) with B
// double-buffered and cross-tile prefetched. Leaky + bf16 -> h4b row-major.
// Kills k_aggregate + the 32MB aggb round-trip + a launch gap.
__global__ __launch_bounds__(512, 4) void fused_layer4(
        const unsigned short* __restrict__ hs,   // in table, chunk-major [4][N][64]
        const int* __restrict__ row_ptr,
        const int* __restrict__ csr_src,
        const float* __restrict__ nd,
        const unsigned short* __restrict__ Bt,   // W4t [1024][256]
        const float* __restrict__ bias,          // b4 [1024]
        unsigned short* __restrict__ h4) {       // [N][1024] bf16
    __shared__ __align__(16) unsigned short At[8 * 2048];
    __shared__ __align__(16) unsigned short Bs[2][256 * 32];
    __shared__ int eIdx[2048];
    __shared__ int rp[65];
    const int tid = threadIdx.x;
    const int lane = tid & 63;
    const int w = tid >> 6;
    const int n0 = blockIdx.x * 64;
    const int K = 256;

    const int pr = lane >> 3;
    const int uu = (lane & 7) ^ pr;
    const int rowInGrp = pr * 2 + (uu >> 2);
    const int kc = (uu & 3) * 8;
    const int bBase = (w * 32) * 32;
#define STAGEB4(buf_, ct_, koff_)                                                        \
    {                                                                                    \
        const unsigned short* gB = Bt + (size_t)((ct_) * 256 + w * 32 + rowInGrp) * K + kc; \
        unsigned short* lB = Bs[buf_] + bBase;                                           \
        __builtin_amdgcn_global_load_lds((const GLOBAL_AS short*)(gB + (koff_)),         \
                                         (LDS_AS short*)lB, 16, 0, 0);                   \
        __builtin_amdgcn_global_load_lds((const GLOBAL_AS short*)(gB + (koff_) + (size_t)16 * K), \
                                         (LDS_AS short*)(lB + 16 * 32), 16, 0, 0);       \
    }
    STAGEB4(0, 0, 0)

    if (tid <= 64) rp[tid] = row_ptr[n0 + tid];
    __syncthreads();
    const int ebeg = rp[0];
    const int ecount = rp[64] - ebeg;
    const int ecached = ecount < 2048 ? ecount : 2048;
    for (int i = tid; i < ecached; i += 512) eIdx[i] = csr_src[ebeg + i];
    __syncthreads();

    const int r = tid >> 3;
    const int fs = tid & 7;
    const int beg = rp[r] - ebeg, end = rp[r + 1] - ebeg;
    const float sc = nd[n0 + r];
    const int rowpair = r >> 1;
    unsigned short* atp = At + rowpair * 64 +
                          (((((r & 1) << 2) | (fs & 3)) ^ (rowpair & 7)) << 3);

    auto sweep = [&](auto fetch) {
        for (int c = 0; c < 4; c++) {
            const unsigned short* hp = hs + (size_t)c * (N_NODES * 64) + fs * 8;
            float acc[8];
#pragma unroll
            for (int k = 0; k < 8; k++) acc[k] = 0.f;
            int e = beg;
            for (; e + 8 <= end; e += 8) {
                int s0 = fetch(e),     s1 = fetch(e + 1), s2 = fetch(e + 2), s3 = fetch(e + 3);
                int s4 = fetch(e + 4), s5 = fetch(e + 5), s6 = fetch(e + 6), s7 = fetch(e + 7);
                short8 v0 = *(const short8*)(hp + (size_t)s0 * 64);
                short8 v1 = *(const short8*)(hp + (size_t)s1 * 64);
                short8 v2 = *(const short8*)(hp + (size_t)s2 * 64);
                short8 v3 = *(const short8*)(hp + (size_t)s3 * 64);
                short8 v4 = *(const short8*)(hp + (size_t)s4 * 64);
                short8 v5 = *(const short8*)(hp + (size_t)s5 * 64);
                short8 v6 = *(const short8*)(hp + (size_t)s6 * 64);
                short8 v7 = *(const short8*)(hp + (size_t)s7 * 64);
#pragma unroll
                for (int k = 0; k < 8; k++)
                    acc[k] += ((bf2f((unsigned short)v0[k]) + bf2f((unsigned short)v1[k])) +
                               (bf2f((unsigned short)v2[k]) + bf2f((unsigned short)v3[k]))) +
                              ((bf2f((unsigned short)v4[k]) + bf2f((unsigned short)v5[k])) +
                               (bf2f((unsigned short)v6[k]) + bf2f((unsigned short)v7[k])));
            }
            for (; e + 2 <= end; e += 2) {
                int s0 = fetch(e), s1 = fetch(e + 1);
                short8 v0 = *(const short8*)(hp + (size_t)s0 * 64);
                short8 v1 = *(const short8*)(hp + (size_t)s1 * 64);
#pragma unroll
                for (int k = 0; k < 8; k++)
                    acc[k] += bf2f((unsigned short)v0[k]) + bf2f((unsigned short)v1[k]);
            }
            if (e < end) {
                int s = fetch(e);
                short8 v = *(const short8*)(hp + (size_t)s * 64);
#pragma unroll
                for (int k = 0; k < 8; k++) acc[k] += bf2f((unsigned short)v[k]);
            }
            short8 o;
#pragma unroll
            for (int k = 0; k < 8; k++) o[k] = (short)f2bf(acc[k] * sc);
            *(short8*)(atp + (c * 2 + (fs >> 2)) * 2048) = o;
        }
    };
    if (ecount <= 2048)
        sweep([&](int e) { return eIdx[e]; });
    else
        sweep([&](int e) { return csr_src[ebeg + e]; });

    const int wr = (w >> 2) * 32;
    const int wc = (w & 3) * 64;
    const int q = lane >> 4;
    const int ln = lane & 15;
    const int uf = (((ln & 1) << 2) | q) ^ ((ln >> 1) & 7);

    int buf = 0;
    for (int ct = 0; ct < 4; ct++) {
        floatx4 acc2[2][4];
#pragma unroll
        for (int i = 0; i < 2; i++)
#pragma unroll
            for (int j = 0; j < 4; j++) acc2[i][j] = (floatx4){0.f, 0.f, 0.f, 0.f};
        for (int k0 = 0; k0 < K; k0 += 32) {
            __syncthreads();
            if (k0 + 32 < K) {
                STAGEB4(buf ^ 1, ct, k0 + 32)
            } else if (ct < 3) {
                STAGEB4(buf ^ 1, ct + 1, 0)
            }
            const unsigned short* rA = At + (k0 >> 5) * 2048;
            const unsigned short* rB = Bs[buf];
            short8 af[2], bfr[4];
#pragma unroll
            for (int i = 0; i < 2; i++)
                af[i] = *(const short8*)(rA + (((wr + i * 16 + ln) >> 1) << 6) + uf * 8);
#pragma unroll
            for (int j = 0; j < 4; j++)
                bfr[j] = *(const short8*)(rB + (((wc + j * 16 + ln) >> 1) << 6) + uf * 8);
#pragma unroll
            for (int i = 0; i < 2; i++)
#pragma unroll
                for (int j = 0; j < 4; j++)
                    acc2[i][j] = __builtin_amdgcn_mfma_f32_16x16x32_bf16(af[i], bfr[j], acc2[i][j], 0, 0, 0);
            buf ^= 1;
        }
        // epilogue for this column tile: bias + leaky -> bf16
#pragma unroll
        for (int i = 0; i < 2; i++) {
#pragma unroll
            for (int rr = 0; rr < 4; rr++) {
                int row = wr + i * 16 + q * 4 + rr;
#pragma unroll
                for (int j = 0; j < 4; j++) {
                    int col = ct * 256 + wc + j * 16 + ln;
                    float v = acc2[i][j][rr] + bias[col];
                    v = v >= 0.f ? v : 0.01f * v;
                    h4[(size_t)(n0 + row) * 1024 + col] = f2bf(v);
                }
            }
        }
    }
#undef STAGEB4
}

// ------------------------------------------------ heads GEMM, K-split x8 -> fp32 partials
__global__ __launch_bounds__(256) void gemm_heads(
        const unsigned short* __restrict__ A,   // pooledb [128][1024] bf16
        const unsigned short* __restrict__ Bt,  // [Wmt;Wst] [2048][1024] bf16
        float* __restrict__ P) {                // [8][128][2048] fp32
    __shared__ __align__(16) unsigned short As[2][128 * 32];
    __shared__ __align__(16) unsigned short Bs[2][128 * 32];
    const int tid = threadIdx.x;
    const int lane = tid & 63;
    const int w = tid >> 6;
    const int wr = (w >> 1) * 64;
    const int wc = (w & 1) * 64;
    const int colBase = blockIdx.x * 128;
    const int ks = blockIdx.y;
    const int K = 1024;

    floatx4 acc[4][4];
#pragma unroll
    for (int i = 0; i < 4; i++)
#pragma unroll
        for (int j = 0; j < 4; j++) acc[i][j] = (floatx4){0.f, 0.f, 0.f, 0.f};

    const int pr = lane >> 3;
    const int uu = (lane & 7) ^ pr;
    const int srow = w * 32 + pr * 2 + (uu >> 2);
    const int kc = (uu & 3) * 8;
    const unsigned short* gA = A + (size_t)srow * K + ks * 128 + kc;
    const unsigned short* gB = Bt + (size_t)(colBase + srow) * K + ks * 128 + kc;
    const int wbase = (w * 32) * 32;

    const int q = lane >> 4;
    const int ln = lane & 15;
    const int uf = (((ln & 1) << 2) | q) ^ ((ln >> 1) & 7);

    {
        unsigned short* lA = As[0] + wbase;
        unsigned short* lB = Bs[0] + wbase;
        __builtin_amdgcn_global_load_lds((const GLOBAL_AS short*)(gA),
                                         (LDS_AS short*)lA, 16, 0, 0);
        __builtin_amdgcn_global_load_lds((const GLOBAL_AS short*)(gA + (size_t)16 * K),
                                         (LDS_AS short*)(lA + 16 * 32), 16, 0, 0);
        __builtin_amdgcn_global_load_lds((const GLOBAL_AS short*)(gB),
                                         (LDS_AS short*)lB, 16, 0, 0);
        __builtin_amdgcn_global_load_lds((const GLOBAL_AS short*)(gB + (size_t)16 * K),
                                         (LDS_AS short*)(lB + 16 * 32), 16, 0, 0);
    }

    int buf = 0;
    for (int k0 = 0; k0 < 128; k0 += 32) {
        __syncthreads();
        if (k0 + 32 < 128) {
            unsigned short* lA = As[buf ^ 1] + wbase;
            unsigned short* lB = Bs[buf ^ 1] + wbase;
            __builtin_amdgcn_global_load_lds((const GLOBAL_AS short*)(gA + k0 + 32),
                                             (LDS_AS short*)lA, 16, 0, 0);
            __builtin_amdgcn_global_load_lds((const GLOBAL_AS short*)(gA + k0 + 32 + (size_t)16 * K),
                                             (LDS_AS short*)(lA + 16 * 32), 16, 0, 0);
            __builtin_amdgcn_global_load_lds((const GLOBAL_AS short*)(gB + k0 + 32),
                                             (LDS_AS short*)lB, 16, 0, 0);
            __builtin_amdgcn_global_load_lds((const GLOBAL_AS short*)(gB + k0 + 32 + (size_t)16 * K),
                                             (LDS_AS short*)(lB + 16 * 32), 16, 0, 0);
        }
        const unsigned short* rA = As[buf];
        const unsigned short* rB = Bs[buf];
        short8 af[4], bfr[4];
#pragma unroll
        for (int i = 0; i < 4; i++)
            af[i] = *(const short8*)(rA + (((wr + i * 16 + ln) >> 1) << 6) + uf * 8);
#pragma unroll
        for (int j = 0; j < 4; j++)
            bfr[j] = *(const short8*)(rB + (((wc + j * 16 + ln) >> 1) << 6) + uf * 8);
#pragma unroll
        for (int i = 0; i < 4; i++)
#pragma unroll
            for (int j = 0; j < 4; j++)
                acc[i][j] = __builtin_amdgcn_mfma_f32_16x16x32_bf16(af[i], bfr[j], acc[i][j], 0, 0, 0);
        buf ^= 1;
    }
    float* Pk = P + (size_t)ks * 128 * 2048;
#pragma unroll
    for (int i = 0; i < 4; i++) {
#pragma unroll
        for (int j = 0; j < 4; j++) {
#pragma unroll
            for (int r = 0; r < 4; r++) {
                int row = wr + i * 16 + q * 4 + r;
                int col = colBase + wc + j * 16 + ln;
                Pk[(size_t)row * 2048 + col] = acc[i][j][r];
            }
        }
    }
}

__global__ __launch_bounds__(256) void k_heads_reduce(
        const float* __restrict__ P, const float* __restrict__ bm,
        const float* __restrict__ bsd, float* __restrict__ out) {
    int idx = blockIdx.x * 256 + threadIdx.x;
    int row = idx >> 9;
    int col = (idx & 511) * 4;
    floatx4 s = (floatx4){0.f, 0.f, 0.f, 0.f};
#pragma unroll
    for (int p = 0; p < 8; p++)
        s += *(const floatx4*)(P + (size_t)p * 128 * 2048 + (size_t)row * 2048 + col);
    bool hi = col >= 1024;
    const float* bias = hi ? bsd : bm;
    int bc = hi ? col - 1024 : col;
    s += *(const floatx4*)(bias + bc);
    float* o = hi ? (out + (size_t)128 * 1024 + (size_t)row * 1024 + bc)
                  : (out + (size_t)row * 1024 + col);
    *(floatx4*)o = s;
}

// ------------------------------------------------ fused per-node LN(1024) + partial mean-pool
__global__ __launch_bounds__(256) void k_lnpool(const unsigned short* __restrict__ h4,
                                                float* __restrict__ partial) {
    const int g = blockIdx.y, p = blockIdx.x;
    const int w = threadIdx.x >> 6, lane = threadIdx.x & 63;
    float acc[16];
#pragma unroll
    for (int k = 0; k < 16; k++) acc[k] = 0.f;
    for (int i = 0; i < 8; i++) {
        int node = (g * 8 + p) * 32 + w * 8 + i;
        const unsigned short* row = h4 + (size_t)node * 1024 + lane * 16;
        short8 a = *(const short8*)row;
        short8 b = *(const short8*)(row + 8);
        float v[16];
#pragma unroll
        for (int k = 0; k < 8; k++) v[k] = bf2f((unsigned short)a[k]);
#pragma unroll
        for (int k = 0; k < 8; k++) v[8 + k] = bf2f((unsigned short)b[k]);
        float s = 0.f, s2 = 0.f;
#pragma unroll
        for (int k = 0; k < 16; k++) { s += v[k]; s2 += v[k] * v[k]; }
#pragma unroll
        for (int off = 32; off > 0; off >>= 1) {
            s += __shfl_down(s, off);
            s2 += __shfl_down(s2, off);
        }
        s = __shfl(s, 0);
        s2 = __shfl(s2, 0);
        float mu = s * (1.0f / 1024.0f);
        float var = s2 * (1.0f / 1024.0f) - mu * mu;
        float rs = rsqrtf(var + 1e-5f);
#pragma unroll
        for (int k = 0; k < 16; k++) acc[k] += (v[k] - mu) * rs;
    }
    __shared__ float red[4][1024];
    float* my = red[w] + lane * 16;
#pragma unroll
    for (int k = 0; k < 16; k++) my[k] = acc[k];
    __syncthreads();
    int t = threadIdx.x;
    floatx4 o = (floatx4){0.f, 0.f, 0.f, 0.f};
#pragma unroll
    for (int w2 = 0; w2 < 4; w2++) {
        const floatx4 v = *(const floatx4*)(red[w2] + t * 4);
        o += v;
    }
    __builtin_nontemporal_store(o, (floatx4*)(partial + (size_t)(g * 8 + p) * 1024 + t * 4));
}

__global__ __launch_bounds__(256) void k_pool_final(const float* __restrict__ partial,
                                                    unsigned short* __restrict__ pooledb) {
    int g = blockIdx.x, t = threadIdx.x;
    int wave = t >> 6;
    float4 a = make_float4(0.f, 0.f, 0.f, 0.f);
    for (int p = 0; p < 8; p++) {
        float4 v = *(const float4*)(partial + (size_t)(g * 8 + p) * 1024 + t * 4);
        a.x += v.x; a.y += v.y; a.z += v.z; a.w += v.w;
    }
    const float invn = 1.0f / 256.0f;
    a.x *= invn; a.y *= invn; a.z *= invn; a.w *= invn;
    float s = a.x + a.y + a.z + a.w;
    float s2 = a.x * a.x + a.y * a.y + a.z * a.z + a.w * a.w;
#pragma unroll
    for (int off = 32; off > 0; off >>= 1) {
        s += __shfl_down(s, off);
        s2 += __shfl_down(s2, off);
    }
    __shared__ float ss[4], ss2[4];
    if ((t & 63) == 0) { ss[wave] = s; ss2[wave] = s2; }
    __syncthreads();
    if (t == 0) {
        float tt = 0.f, tt2 = 0.f;
        for (int w = 0; w < 4; w++) { tt += ss[w]; tt2 += ss2[w]; }
        float mu = tt / 1024.f;
        float var = tt2 / 1024.f - mu * mu;
        ss[0] = mu;
        ss2[0] = rsqrtf(var + 1e-5f);
    }
    __syncthreads();
    float mu = ss[0], inv = ss2[0];
    ushort4 o;
    o.x = f2bf((a.x - mu) * inv); o.y = f2bf((a.y - mu) * inv);
    o.z = f2bf((a.z - mu) * inv); o.w = f2bf((a.w - mu) * inv);
    *(ushort4*)(pooledb + (size_t)g * 1024 + t * 4) = o;
}

// ---------------------------------------------------------------- launch
extern "C" void kernel_launch(void* const* d_in, const int* in_sizes, int n_in,
                              void* d_out, int out_size, void* d_ws, size_t ws_size,
                              hipStream_t stream) {
    const float* x  = (const float*)d_in[0];
    const int*   src = (const int*)d_in[1];
    const int*   dst = (const int*)d_in[2];
    const float* W1 = (const float*)d_in[3];  const float* b1 = (const float*)d_in[4];
    const float* W2 = (const float*)d_in[5];  const float* b2 = (const float*)d_in[6];
    const float* W3 = (const float*)d_in[7];  const float* b3 = (const float*)d_in[8];
    const float* W4 = (const float*)d_in[9];  const float* b4 = (const float*)d_in[10];
    const float* Wm = (const float*)d_in[11]; const float* bm = (const float*)d_in[12];
    const float* Wsd = (const float*)d_in[13]; const float* bsd = (const float*)d_in[14];
    float* out = (float*)d_out;

    char* w = (char*)d_ws;
    unsigned short* hsbA = (unsigned short*)w; w += (size_t)N_NODES * 256 * 2;
    unsigned short* hsbB = (unsigned short*)w; w += (size_t)N_NODES * 256 * 2;
    unsigned short* h4b  = (unsigned short*)w; w += (size_t)N_NODES * 1024 * 2;
    float* partial = (float*)w; w += (size_t)128 * 8 * 1024 * 4;
    unsigned short* pooledb = (unsigned short*)w; w += (size_t)128 * 1024 * 2;
    unsigned short* W1t = (unsigned short*)w; w += (size_t)256 * 256 * 2;
    unsigned short* W2t = (unsigned short*)w; w += (size_t)256 * 256 * 2;
    unsigned short* W3t = (unsigned short*)w; w += (size_t)256 * 256 * 2;
    unsigned short* W4t = (unsigned short*)w; w += (size_t)256 * 1024 * 2;
    unsigned short* Wmt = (unsigned short*)w; w += (size_t)1024 * 1024 * 2;  // Wst must follow
    unsigned short* Wst = (unsigned short*)w; w += (size_t)1024 * 1024 * 2;  // contiguous: cat
    float* ns     = (float*)w; w += (size_t)N_NODES * 4;
    float* nd     = (float*)w; w += (size_t)N_NODES * 4;
    unsigned int* histOut32 = (unsigned int*)w; w += (size_t)128 * 8192 * 4;
    unsigned int* histIn32  = (unsigned int*)w; w += (size_t)128 * 8192 * 4;
    unsigned int* pre32     = (unsigned int*)w; w += (size_t)128 * 8192 * 4;
    unsigned int* partIn    = (unsigned int*)w; w += (size_t)8 * 8192 * 4;
    unsigned int* partOut   = (unsigned int*)w; w += (size_t)8 * 8192 * 4;
    int* blkSum   = (int*)w;   w += (size_t)64 * 4;
    int* in_deg   = (int*)w;   w += (size_t)N_NODES * 4;
    int* row_ptr  = (int*)w;   w += (size_t)(N_NODES + 1) * 4;
    int* csr_src  = (int*)w;   w += (size_t)N_EDGES * 4;
    // heads partials reuse hist area (dead after k_place): 8 MB needed
    float* headp = (float*)histOut32;

    // weights (independent of graph work)
    TransDescs td;
    td.W[0] = W1; td.W[1] = W2; td.W[2] = W3; td.W[3] = W4; td.W[4] = Wm; td.W[5] = Wsd;
    td.Wt[0] = W1t; td.Wt[1] = W2t; td.Wt[2] = W3t; td.Wt[3] = W4t; td.Wt[4] = Wmt; td.Wt[5] = Wst;
    td.K[0] = 256; td.K[1] = 256; td.K[2] = 256; td.K[3] = 256; td.K[4] = 1024; td.K[5] = 1024;
    td.N[0] = 256; td.N[1] = 256; td.N[2] = 256; td.N[3] = 1024; td.N[4] = 1024; td.N[5] = 1024;
    td.end[0] = 64; td.end[1] = 128; td.end[2] = 192; td.end[3] = 448; td.end[4] = 1472; td.end[5] = 2496;
    k_transpose_all<<<2496, 256, 0, stream>>>(td);

    // CSR preprocessing (wide, atomic-free, deterministic)
    k_hist<<<128, 256, 0, stream>>>(src, dst, histOut32, histIn32);
    k_merge_p1<<<dim3(32, 8), 256, 0, stream>>>(histIn32, histOut32, partIn, partOut);
    k_merge_p2<<<dim3(32, 8), 256, 0, stream>>>(histIn32, partIn, partOut, pre32, in_deg, ns, nd);
    k_scanA<<<32, 256, 0, stream>>>(in_deg, row_ptr, blkSum);
    k_scanC<<<32, 256, 0, stream>>>(blkSum, row_ptr);
    k_place<<<128, 256, 0, stream>>>(src, dst, pre32, row_ptr, csr_src);

    // layer-1 gather table: x * ns -> bf16 (chunk-major slabs)
    k_scale_x<<<N_NODES * 256 / 1024, 256, 0, stream>>>(x, ns, hsbA);

    // layers 1-3: fused gather+GEMM+LN, ping-pong tables
    const unsigned short* Wts[3] = {W1t, W2t, W3t};
    const float* bs3[3] = {b1, b2, b3};
    unsigned short* tin = hsbA;
    unsigned short* tout = hsbB;
    for (int l = 0; l < 3; l++) {
        fused_layer<<<N_NODES / 64, 512, 0, stream>>>(tin, row_ptr, csr_src, nd,
                                                      Wts[l], bs3[l], ns, tout);
        unsigned short* tmp = tin; tin = tout; tout = tmp;
    }

    // layer 4 fused: gather + 4 col-tiles GEMM + leaky -> h4b
    fused_layer4<<<N_NODES / 64, 512, 0, stream>>>(tin, row_ptr, csr_src, nd,
                                                   W4t, b4, h4b);

    // per-node LN + mean pool + final LN -> bf16
    k_lnpool<<<dim3(8, 128), 256, 0, stream>>>(h4b, partial);
    k_pool_final<<<128, 256, 0, stream>>>(partial, pooledb);

    // heads: K-split x8 GEMM (128 blocks) -> fp32 partials -> reduce+bias+split
    gemm_heads<<<dim3(16, 8), 256, 0, stream>>>(pooledb, Wmt, headp);
    k_heads_reduce<<<256, 256, 0, stream>>>(headp, bm, bsd, out);
}